// Round 1
// baseline (6865.272 us; speedup 1.0000x reference)
//
#include <hip/hip_runtime.h>
#include <math.h>

static constexpr int Cdim = 32;   // C
static constexpr int NBES = 8;    // NB
static constexpr int HDIM = 64;   // H
static constexpr int ZDIM = 10;   // Z

__device__ __forceinline__ float silu_f(float x) {
    return x / (1.0f + __expf(-x));
}

// ---------------- node init: elem, h=W_embed[elem], energy=atomic_E[elem] ----------------
__global__ __launch_bounds__(256)
void k_node_init(const float* __restrict__ attrs, const float* __restrict__ W_embed,
                 const float* __restrict__ atomE, int* __restrict__ elem,
                 float* __restrict__ h, float* __restrict__ energy,
                 int* __restrict__ cnt, int N)
{
    int n = blockIdx.x * blockDim.x + threadIdx.x;
    if (n == 0) *cnt = 0;            // reset active-edge counter every call
    if (n >= N) return;
    int e = 0; float best = -1.0f;
    #pragma unroll
    for (int z = 0; z < ZDIM; ++z) {
        float v = attrs[n * ZDIM + z];
        if (v > best) { best = v; e = z; }
    }
    elem[n] = e;
    #pragma unroll
    for (int c = 0; c < Cdim; ++c) h[n * Cdim + c] = W_embed[e * Cdim + c];
    energy[n] = atomE[e];
}

// ---------------- ZBL pair energy + active edge compaction ----------------
__global__ __launch_bounds__(256)
void k_edge_zbl(const float* __restrict__ pos, const int* __restrict__ snd,
                const int* __restrict__ rcv, const int* __restrict__ elem,
                float* __restrict__ energy, int* __restrict__ cnt,
                int* __restrict__ active, int E)
{
    int e = blockIdx.x * blockDim.x + threadIdx.x;
    if (e >= E) return;
    int s = snd[e], t = rcv[e];
    float dx = pos[3*t+0] - pos[3*s+0];
    float dy = pos[3*t+1] - pos[3*s+1];
    float dz = pos[3*t+2] - pos[3*s+2];
    float r  = sqrtf(dx*dx + dy*dy + dz*dz + 1e-12f);
    float u  = r / 5.0f;
    if (!(u < 1.0f)) return;          // fcut==0 -> zero ZBL, zero R, zero msg
    float u2 = u*u, u5 = u2*u2*u;
    float fcut = 1.0f - 21.0f*u5 + 35.0f*u5*u - 15.0f*u5*u2;
    float zi = (float)(elem[s] + 1);
    float zj = (float)(elem[t] + 1);
    float a  = 0.4685f / (powf(zi, 0.23f) + powf(zj, 0.23f));
    float xx = r / a;
    float phi = 0.1818f*expf(-3.2f*xx) + 0.5099f*expf(-0.9423f*xx)
              + 0.2802f*expf(-0.4029f*xx) + 0.02817f*expf(-0.2016f*xx);
    float v = 14.3996f * zi * zj / r * phi * fcut;
    atomicAdd(&energy[t], 0.5f * v);
    int slot = atomicAdd(cnt, 1);
    active[slot] = e;
}

// ---------------- zero the A accumulator (feats1 slot of d_out) ----------------
__global__ __launch_bounds__(256)
void k_zero_A(float4* __restrict__ f4, int N)   // f4 = (float4*)(d_out + N)
{
    int t = blockIdx.x * blockDim.x + threadIdx.x;
    if (t >= N * 72) return;
    int n = t / 72, j = t - n * 72;
    f4[(size_t)n * 144 + 72 + j] = make_float4(0.f, 0.f, 0.f, 0.f);
}

// ---------------- h1 = h @ Wlin[i] ----------------
__global__ __launch_bounds__(256)
void k_h1(const float* __restrict__ h, const float* __restrict__ Wlin,
          float* __restrict__ h1, int N)
{
    __shared__ float sW[Cdim * Cdim];
    for (int t = threadIdx.x; t < Cdim * Cdim; t += 256) sW[t] = Wlin[t];
    __syncthreads();
    int n = blockIdx.x * blockDim.x + threadIdx.x;
    if (n >= N) return;
    float hv[Cdim];
    #pragma unroll
    for (int c4 = 0; c4 < 8; ++c4) {
        float4 v = *(const float4*)(h + (size_t)n * Cdim + c4 * 4);
        hv[c4*4+0] = v.x; hv[c4*4+1] = v.y; hv[c4*4+2] = v.z; hv[c4*4+3] = v.w;
    }
    float acc[Cdim];
    #pragma unroll
    for (int d = 0; d < Cdim; ++d) acc[d] = 0.f;
    #pragma unroll
    for (int c = 0; c < Cdim; ++c) {
        float hc = hv[c];
        #pragma unroll
        for (int d = 0; d < Cdim; ++d) acc[d] += hc * sW[c * Cdim + d];
    }
    #pragma unroll
    for (int d4 = 0; d4 < 8; ++d4)
        *(float4*)(h1 + (size_t)n * Cdim + d4 * 4) =
            make_float4(acc[d4*4], acc[d4*4+1], acc[d4*4+2], acc[d4*4+3]);
}

// ---------------- per active edge: radial MLP + message scatter ----------------
__global__ __launch_bounds__(256)
void k_edge_msg(const int* __restrict__ active, const int* __restrict__ cnt,
                const int* __restrict__ snd, const int* __restrict__ rcv,
                const float* __restrict__ pos, const float* __restrict__ h1,
                const float* __restrict__ Wr0, const float* __restrict__ Wr1,
                const float* __restrict__ Wr2, const float* __restrict__ Wr3,
                float* __restrict__ Abase)   // Abase = d_out + N, row stride 576, A at +288
{
    int nact = *cnt;
    if ((int)(blockIdx.x * 256) >= nact) return;   // uniform early-out for idle blocks
    __shared__ float sW0[NBES * HDIM];
    __shared__ float sW1[HDIM * HDIM];
    __shared__ float sW2[HDIM * HDIM];
    __shared__ float sW3[HDIM * 96];
    for (int t = threadIdx.x; t < NBES * HDIM; t += 256) sW0[t] = Wr0[t];
    for (int t = threadIdx.x; t < HDIM * HDIM; t += 256) { sW1[t] = Wr1[t]; sW2[t] = Wr2[t]; }
    for (int t = threadIdx.x; t < HDIM * 96; t += 256) sW3[t] = Wr3[t];
    __syncthreads();
    int idx = blockIdx.x * 256 + threadIdx.x;
    if (idx >= nact) return;
    int e = active[idx];
    int s = snd[e], t = rcv[e];

    float dx = pos[3*t+0] - pos[3*s+0];
    float dy = pos[3*t+1] - pos[3*s+1];
    float dz = pos[3*t+2] - pos[3*s+2];
    float r  = sqrtf(dx*dx + dy*dy + dz*dz + 1e-12f);
    float inv_r = 1.0f / r;
    float ux = dx*inv_r, uy = dy*inv_r, uz = dz*inv_r;
    float u  = r / 5.0f;
    float u2 = u*u, u5 = u2*u2*u;
    float fcut = 1.0f - 21.0f*u5 + 35.0f*u5*u - 15.0f*u5*u2;

    // R = sqrt(2/5) * sin(n*pi*r/5)/r * fcut
    float Rb[NBES];
    float coef = 0.632455532f * inv_r * fcut;
    #pragma unroll
    for (int k = 0; k < NBES; ++k)
        Rb[k] = coef * __sinf((float)(k+1) * 0.628318531f * r);

    const float s3 = 1.73205081f, s5 = 2.23606798f, s15 = 3.87298335f;
    float sh0 = 1.0f;
    float sh1 = s3 * ux, sh2 = s3 * uy, sh3 = s3 * uz;
    float sh4 = s15 * ux * uy, sh5 = s15 * uy * uz;
    float sh6 = 0.5f * s5 * (3.0f * uz * uz - 1.0f);
    float sh7 = s15 * ux * uz;
    float sh8 = 0.5f * s15 * (ux * ux - uy * uy);

    float a[HDIM], b[HDIM];
    // L1: 8 -> 64, silu
    #pragma unroll
    for (int j0 = 0; j0 < HDIM; j0 += 4) {
        float q0=0.f,q1=0.f,q2=0.f,q3=0.f;
        #pragma unroll
        for (int k = 0; k < NBES; ++k) {
            float av = Rb[k];
            const float* wp = sW0 + k * HDIM + j0;
            q0 += av*wp[0]; q1 += av*wp[1]; q2 += av*wp[2]; q3 += av*wp[3];
        }
        a[j0]=silu_f(q0); a[j0+1]=silu_f(q1); a[j0+2]=silu_f(q2); a[j0+3]=silu_f(q3);
    }
    // L2: 64 -> 64, silu
    #pragma unroll
    for (int j0 = 0; j0 < HDIM; j0 += 4) {
        float q0=0.f,q1=0.f,q2=0.f,q3=0.f;
        #pragma unroll
        for (int k = 0; k < HDIM; ++k) {
            float av = a[k];
            const float* wp = sW1 + k * HDIM + j0;
            q0 += av*wp[0]; q1 += av*wp[1]; q2 += av*wp[2]; q3 += av*wp[3];
        }
        b[j0]=silu_f(q0); b[j0+1]=silu_f(q1); b[j0+2]=silu_f(q2); b[j0+3]=silu_f(q3);
    }
    // L3: 64 -> 64, silu
    #pragma unroll
    for (int j0 = 0; j0 < HDIM; j0 += 4) {
        float q0=0.f,q1=0.f,q2=0.f,q3=0.f;
        #pragma unroll
        for (int k = 0; k < HDIM; ++k) {
            float av = b[k];
            const float* wp = sW2 + k * HDIM + j0;
            q0 += av*wp[0]; q1 += av*wp[1]; q2 += av*wp[2]; q3 += av*wp[3];
        }
        a[j0]=silu_f(q0); a[j0+1]=silu_f(q1); a[j0+2]=silu_f(q2); a[j0+3]=silu_f(q3);
    }
    // sender features
    float h1r[Cdim];
    #pragma unroll
    for (int c4 = 0; c4 < 8; ++c4) {
        float4 v = *(const float4*)(h1 + (size_t)s * Cdim + c4 * 4);
        h1r[c4*4+0] = v.x; h1r[c4*4+1] = v.y; h1r[c4*4+2] = v.z; h1r[c4*4+3] = v.w;
    }
    // L4 (64 -> 96, no activation) fused with scatter
    float* Arow = Abase + (size_t)t * 576 + 288;
    #pragma unroll
    for (int c0 = 0; c0 < Cdim; c0 += 4) {
        float w0[4] = {0,0,0,0}, w1v[4] = {0,0,0,0}, w2v[4] = {0,0,0,0};
        #pragma unroll
        for (int k = 0; k < HDIM; ++k) {
            float av = a[k];
            const float* wp = sW3 + k * 96;
            #pragma unroll
            for (int j = 0; j < 4; ++j) {
                w0[j]  += av * wp[c0 + j];
                w1v[j] += av * wp[32 + c0 + j];
                w2v[j] += av * wp[64 + c0 + j];
            }
        }
        #pragma unroll
        for (int j = 0; j < 4; ++j) {
            int c = c0 + j;
            float m0 = h1r[c] * w0[j];
            float m1 = h1r[c] * w1v[j];
            float m2 = h1r[c] * w2v[j];
            atomicAdd(Arow + 0*Cdim + c, sh0 * m0);
            atomicAdd(Arow + 1*Cdim + c, sh1 * m1);
            atomicAdd(Arow + 2*Cdim + c, sh2 * m1);
            atomicAdd(Arow + 3*Cdim + c, sh3 * m1);
            atomicAdd(Arow + 4*Cdim + c, sh4 * m2);
            atomicAdd(Arow + 5*Cdim + c, sh5 * m2);
            atomicAdd(Arow + 6*Cdim + c, sh6 * m2);
            atomicAdd(Arow + 7*Cdim + c, sh7 * m2);
            atomicAdd(Arow + 8*Cdim + c, sh8 * m2);
        }
    }
}

// ---------------- out[n,m,:] = (A[n,m,:]/16) @ Wprod[L[m]]  for m=1..8 ----------------
__global__ __launch_bounds__(256)
void k_out_m(float* AO, const float* __restrict__ Wprod, int N, int outslot)
{
    __shared__ float sW[3 * Cdim * Cdim];
    for (int t = threadIdx.x; t < 3 * Cdim * Cdim; t += 256) sW[t] = Wprod[t];
    __syncthreads();
    int t = blockIdx.x * blockDim.x + threadIdx.x;
    if (t >= N * 8) return;
    int m = (t & 7) + 1;
    int n = t >> 3;
    int l = (m <= 3) ? 1 : 2;
    const float* Ar = AO + (size_t)n * 576 + 288 + m * Cdim;
    float Av[Cdim];
    #pragma unroll
    for (int c4 = 0; c4 < 8; ++c4) {
        float4 v = *(const float4*)(Ar + c4 * 4);
        Av[c4*4+0]=v.x*0.0625f; Av[c4*4+1]=v.y*0.0625f;
        Av[c4*4+2]=v.z*0.0625f; Av[c4*4+3]=v.w*0.0625f;
    }
    float acc[Cdim];
    #pragma unroll
    for (int d = 0; d < Cdim; ++d) acc[d] = 0.f;
    const float* wbase = sW + l * Cdim * Cdim;
    #pragma unroll
    for (int c = 0; c < Cdim; ++c) {
        float av = Av[c];
        #pragma unroll
        for (int d = 0; d < Cdim; ++d) acc[d] += av * wbase[c * Cdim + d];
    }
    float* o = AO + (size_t)n * 576 + outslot + m * Cdim;
    #pragma unroll
    for (int d4 = 0; d4 < 8; ++d4)
        *(float4*)(o + d4 * 4) = make_float4(acc[d4*4], acc[d4*4+1], acc[d4*4+2], acc[d4*4+3]);
}

// ---------------- per-node scalar channel: out0 + poly + sc, energy, h update ----------------
template<int ITER>
__global__ __launch_bounds__(256)
void k_node_scalar(float* AO, const float* h, const int* __restrict__ elem,
                   const float* __restrict__ Wprod0, const float* __restrict__ Wsc,
                   const float* __restrict__ Wp, const float* __restrict__ w_ro1,
                   const float* __restrict__ W_m1, const float* __restrict__ w_m2,
                   float* h_next, float* __restrict__ energy, int N, int outslot)
{
    __shared__ float sW0[Cdim * Cdim];
    __shared__ float sM1[Cdim * 16];
    __shared__ float sm2[16];
    __shared__ float sro[Cdim];
    for (int t = threadIdx.x; t < Cdim * Cdim; t += 256) sW0[t] = Wprod0[t];
    for (int t = threadIdx.x; t < Cdim * 16; t += 256) sM1[t] = W_m1[t];
    if (threadIdx.x < 16) sm2[threadIdx.x] = w_m2[threadIdx.x];
    if (threadIdx.x < Cdim) sro[threadIdx.x] = w_ro1[threadIdx.x];
    __syncthreads();
    int n = blockIdx.x * blockDim.x + threadIdx.x;
    if (n >= N) return;
    int el = elem[n];
    const float* Ar = AO + (size_t)n * 576 + 288;
    float A0[Cdim], hv[Cdim];
    #pragma unroll
    for (int c4 = 0; c4 < 8; ++c4) {
        float4 v = *(const float4*)(Ar + c4 * 4);
        A0[c4*4+0]=v.x*0.0625f; A0[c4*4+1]=v.y*0.0625f;
        A0[c4*4+2]=v.z*0.0625f; A0[c4*4+3]=v.w*0.0625f;
        float4 w = *(const float4*)(h + (size_t)n * Cdim + c4 * 4);
        hv[c4*4+0]=w.x; hv[c4*4+1]=w.y; hv[c4*4+2]=w.z; hv[c4*4+3]=w.w;
    }
    float hs[Cdim];
    #pragma unroll
    for (int d = 0; d < Cdim; ++d) hs[d] = 0.f;
    // out0 = A0 @ Wprod[0]
    #pragma unroll
    for (int c = 0; c < Cdim; ++c) {
        float av = A0[c];
        #pragma unroll
        for (int d = 0; d < Cdim; ++d) hs[d] += av * sW0[c * Cdim + d];
    }
    // sc = h @ Wsc[elem]  (global, cache-served: only 40KB working set)
    const float* Ws = Wsc + (size_t)el * Cdim * Cdim;
    #pragma unroll
    for (int c = 0; c < Cdim; ++c) {
        float hc = hv[c];
        #pragma unroll
        for (int d = 0; d < Cdim; ++d) hs[d] += hc * Ws[c * Cdim + d];
    }
    // poly: sum_k Wp[k][elem][:] * A0^(k+1)
    const float* wp0 = Wp + 0 * (ZDIM * Cdim) + el * Cdim;
    const float* wp1 = Wp + 1 * (ZDIM * Cdim) + el * Cdim;
    const float* wp2 = Wp + 2 * (ZDIM * Cdim) + el * Cdim;
    #pragma unroll
    for (int d = 0; d < Cdim; ++d) {
        float A = A0[d], A2 = A * A;
        hs[d] += wp0[d] * A + wp1[d] * A2 + wp2[d] * (A2 * A);
    }
    // energy readout
    float eadd;
    if (ITER == 0) {
        float acc = 0.f;
        #pragma unroll
        for (int d = 0; d < Cdim; ++d) acc += hs[d] * sro[d];
        eadd = acc;
    } else {
        float acc = 0.f;
        #pragma unroll
        for (int j = 0; j < 16; ++j) {
            float tj = 0.f;
            #pragma unroll
            for (int d = 0; d < Cdim; ++d) tj += hs[d] * sM1[d * 16 + j];
            acc += silu_f(tj) * sm2[j];
        }
        eadd = acc;
    }
    energy[n] += eadd;
    float* o = AO + (size_t)n * 576 + outslot;   // feats slot m=0
    #pragma unroll
    for (int d4 = 0; d4 < 8; ++d4)
        *(float4*)(o + d4 * 4) = make_float4(hs[d4*4], hs[d4*4+1], hs[d4*4+2], hs[d4*4+3]);
    if (ITER == 0) {
        #pragma unroll
        for (int d4 = 0; d4 < 8; ++d4)
            *(float4*)(h_next + (size_t)n * Cdim + d4 * 4) =
                make_float4(hs[d4*4], hs[d4*4+1], hs[d4*4+2], hs[d4*4+3]);
    }
}

extern "C" void kernel_launch(void* const* d_in, const int* in_sizes, int n_in,
                              void* d_out, int out_size, void* d_ws, size_t ws_size,
                              hipStream_t stream)
{
    const float* attrs   = (const float*)d_in[0];
    const float* pos     = (const float*)d_in[1];
    const int*   snd     = (const int*)d_in[2];
    const int*   rcv     = (const int*)d_in[3];
    const float* W_embed = (const float*)d_in[4];
    const float* atomE   = (const float*)d_in[5];
    const float* Wr0     = (const float*)d_in[6];
    const float* Wr1     = (const float*)d_in[7];
    const float* Wr2     = (const float*)d_in[8];
    const float* Wr3     = (const float*)d_in[9];
    const float* Wlin    = (const float*)d_in[10];
    const float* Wsc     = (const float*)d_in[11];
    const float* Wprod   = (const float*)d_in[12];
    const float* Wp      = (const float*)d_in[13];
    const float* w_ro1   = (const float*)d_in[14];
    const float* W_m1    = (const float*)d_in[15];
    const float* w_m2    = (const float*)d_in[16];

    const int N = in_sizes[1] / 3;
    const int E = in_sizes[2];

    float* energy = (float*)d_out;
    float* feats  = (float*)d_out + N;   // N x 576 (feats0 | feats1); A lives in feats1 slot

    char* ws = (char*)d_ws;
    int* cnt    = (int*)ws;
    int* active = (int*)(ws + 256);
    size_t off = 256 + (size_t)E * 4;
    off = (off + 255) & ~(size_t)255;
    int* elem = (int*)(ws + off);
    off += (size_t)N * 4; off = (off + 255) & ~(size_t)255;
    float* h  = (float*)(ws + off); off += (size_t)N * Cdim * 4;
    float* h1 = (float*)(ws + off);

    k_node_init<<<(N + 255)/256, 256, 0, stream>>>(attrs, W_embed, atomE, elem, h, energy, cnt, N);
    k_edge_zbl<<<(E + 255)/256, 256, 0, stream>>>(pos, snd, rcv, elem, energy, cnt, active, E);

    for (int i = 0; i < 2; ++i) {
        k_zero_A<<<(N*72 + 255)/256, 256, 0, stream>>>((float4*)feats, N);
        k_h1<<<(N + 255)/256, 256, 0, stream>>>(h, Wlin + i * Cdim * Cdim, h1, N);
        k_edge_msg<<<(E + 255)/256, 256, 0, stream>>>(active, cnt, snd, rcv, pos, h1,
            Wr0 + i * NBES * HDIM, Wr1 + i * HDIM * HDIM,
            Wr2 + i * HDIM * HDIM, Wr3 + i * HDIM * 96, feats);
        k_out_m<<<(N*8 + 255)/256, 256, 0, stream>>>(feats, Wprod + i * 3 * Cdim * Cdim,
                                                     N, (i == 0) ? 0 : 288);
        if (i == 0)
            k_node_scalar<0><<<(N + 255)/256, 256, 0, stream>>>(feats, h, elem,
                Wprod + 0 * 3072, Wsc + 0 * 10240, Wp + 0 * 960,
                w_ro1, W_m1, w_m2, h, energy, N, 0);
        else
            k_node_scalar<1><<<(N + 255)/256, 256, 0, stream>>>(feats, h, elem,
                Wprod + 1 * 3072, Wsc + 1 * 10240, Wp + 1 * 960,
                w_ro1, W_m1, w_m2, h, energy, N, 288);
    }
}

// Round 2
// 2307.545 us; speedup vs baseline: 2.9751x; 2.9751x over previous
//
#include <hip/hip_runtime.h>
#include <math.h>

static constexpr int Cdim = 32;   // C
static constexpr int NBES = 8;    // NB
static constexpr int HDIM = 64;   // H
static constexpr int ZDIM = 10;   // Z
static constexpr int GNOD = 49;   // nodes per gather block (1021 blocks ~ 4*256)

__device__ __forceinline__ float silu_f(float x) {
    return x / (1.0f + __expf(-x));
}

// ---------------- node init: elem, h=W_embed[elem], energy=atomic_E[elem], deg=0 ----------------
__global__ __launch_bounds__(256)
void k_node_init(const float* __restrict__ attrs, const float* __restrict__ W_embed,
                 const float* __restrict__ atomE, int* __restrict__ elem,
                 float* __restrict__ h, float* __restrict__ energy,
                 int* __restrict__ deg, int N)
{
    int n = blockIdx.x * blockDim.x + threadIdx.x;
    if (n >= N) return;
    int e = 0; float best = -1.0f;
    #pragma unroll
    for (int z = 0; z < ZDIM; ++z) {
        float v = attrs[n * ZDIM + z];
        if (v > best) { best = v; e = z; }
    }
    elem[n] = e;
    #pragma unroll
    for (int c = 0; c < Cdim; ++c) h[n * Cdim + c] = W_embed[e * Cdim + c];
    energy[n] = atomE[e];
    deg[n] = 0;
}

// ---------------- ZBL pair energy + per-receiver degree count (active edges only) ----------------
__global__ __launch_bounds__(256)
void k_edge_zbl(const float* __restrict__ pos, const int* __restrict__ snd,
                const int* __restrict__ rcv, const int* __restrict__ elem,
                float* __restrict__ energy, int* __restrict__ deg, int E)
{
    int e = blockIdx.x * blockDim.x + threadIdx.x;
    if (e >= E) return;
    int s = snd[e], t = rcv[e];
    float dx = pos[3*t+0] - pos[3*s+0];
    float dy = pos[3*t+1] - pos[3*s+1];
    float dz = pos[3*t+2] - pos[3*s+2];
    float r  = sqrtf(dx*dx + dy*dy + dz*dz + 1e-12f);
    float u  = r / 5.0f;
    if (!(u < 1.0f)) return;          // fcut==0 -> zero ZBL, zero msg
    float u2 = u*u, u5 = u2*u2*u;
    float fcut = 1.0f - 21.0f*u5 + 35.0f*u5*u - 15.0f*u5*u2;
    float zi = (float)(elem[s] + 1);
    float zj = (float)(elem[t] + 1);
    float a  = 0.4685f / (powf(zi, 0.23f) + powf(zj, 0.23f));
    float xx = r / a;
    float phi = 0.1818f*expf(-3.2f*xx) + 0.5099f*expf(-0.9423f*xx)
              + 0.2802f*expf(-0.4029f*xx) + 0.02817f*expf(-0.2016f*xx);
    float v = 14.3996f * zi * zj / r * phi * fcut;
    atomicAdd(&energy[t], 0.5f * v);
    atomicAdd(&deg[t], 1);
}

// ---------------- single-block exclusive scan: rowptr/cursor from deg ----------------
__global__ __launch_bounds__(1024)
void k_scan(const int* __restrict__ deg, int* __restrict__ rowptr,
            int* __restrict__ cursor, int N)
{
    __shared__ int wsum[16];
    __shared__ int chunk_base;
    int tid = threadIdx.x;
    int lane = tid & 63, w = tid >> 6;
    if (tid == 0) chunk_base = 0;
    __syncthreads();
    for (int base = 0; base < N; base += 1024) {
        int i = base + tid;
        int v = (i < N) ? deg[i] : 0;
        int s = v;
        #pragma unroll
        for (int d = 1; d < 64; d <<= 1) {
            int u = __shfl_up(s, d);
            if (lane >= d) s += u;
        }
        if (lane == 63) wsum[w] = s;
        __syncthreads();
        if (w == 0 && lane < 16) {
            int x = wsum[lane];
            #pragma unroll
            for (int d = 1; d < 16; d <<= 1) {
                int u = __shfl_up(x, d);
                if (lane >= d) x += u;
            }
            wsum[lane] = x;   // inclusive scan of wave sums
        }
        __syncthreads();
        int wave_off = (w == 0) ? 0 : wsum[w - 1];
        int excl = chunk_base + wave_off + (s - v);
        if (i < N) { rowptr[i] = excl; cursor[i] = excl; }
        int total = wsum[15];
        __syncthreads();
        if (tid == 0) chunk_base += total;
        __syncthreads();
    }
    if (tid == 0) rowptr[N] = chunk_base;
}

// ---------------- place active edges into CSR slots ----------------
__global__ __launch_bounds__(256)
void k_place(const float* __restrict__ pos, const int* __restrict__ snd,
             const int* __restrict__ rcv, int* __restrict__ cursor,
             int* __restrict__ eS, int* __restrict__ eT, int E)
{
    int e = blockIdx.x * blockDim.x + threadIdx.x;
    if (e >= E) return;
    int s = snd[e], t = rcv[e];
    float dx = pos[3*t+0] - pos[3*s+0];
    float dy = pos[3*t+1] - pos[3*s+1];
    float dz = pos[3*t+2] - pos[3*s+2];
    float r  = sqrtf(dx*dx + dy*dy + dz*dz + 1e-12f);
    if (!(r / 5.0f < 1.0f)) return;
    int slot = atomicAdd(&cursor[t], 1);
    eS[slot] = s;
    eT[slot] = t;
}

// ---------------- h1 = h @ Wlin[i] ----------------
__global__ __launch_bounds__(256)
void k_h1(const float* __restrict__ h, const float* __restrict__ Wlin,
          float* __restrict__ h1, int N)
{
    __shared__ float sW[Cdim * Cdim];
    for (int t = threadIdx.x; t < Cdim * Cdim; t += 256) sW[t] = Wlin[t];
    __syncthreads();
    int n = blockIdx.x * blockDim.x + threadIdx.x;
    if (n >= N) return;
    float hv[Cdim];
    #pragma unroll
    for (int c4 = 0; c4 < 8; ++c4) {
        float4 v = *(const float4*)(h + (size_t)n * Cdim + c4 * 4);
        hv[c4*4+0] = v.x; hv[c4*4+1] = v.y; hv[c4*4+2] = v.z; hv[c4*4+3] = v.w;
    }
    float acc[Cdim];
    #pragma unroll
    for (int d = 0; d < Cdim; ++d) acc[d] = 0.f;
    #pragma unroll
    for (int c = 0; c < Cdim; ++c) {
        float hc = hv[c];
        #pragma unroll
        for (int d = 0; d < Cdim; ++d) acc[d] += hc * sW[c * Cdim + d];
    }
    #pragma unroll
    for (int d4 = 0; d4 < 8; ++d4)
        *(float4*)(h1 + (size_t)n * Cdim + d4 * 4) =
            make_float4(acc[d4*4], acc[d4*4+1], acc[d4*4+2], acc[d4*4+3]);
}

// ---------------- gather: per-node-range block, thread-per-edge MLP, LDS accumulate ----------------
__global__ __launch_bounds__(256)
void k_gather(const int* __restrict__ rowptr, const int* __restrict__ eS,
              const int* __restrict__ eT, const float* __restrict__ pos,
              const float* __restrict__ h1,
              const float* __restrict__ Wr0, const float* __restrict__ Wr1,
              const float* __restrict__ Wr2, const float* __restrict__ Wr3,
              float* __restrict__ feats, int N)
{
    __shared__ float sW0[NBES * HDIM];
    __shared__ float sW1[HDIM * HDIM];
    __shared__ float sW2[HDIM * HDIM];
    __shared__ float sW3[HDIM * 96];
    __shared__ float sA[GNOD * 289];   // stride 289: distinct node rows -> distinct banks

    for (int t = threadIdx.x; t < NBES * HDIM; t += 256) sW0[t] = Wr0[t];
    for (int t = threadIdx.x; t < HDIM * HDIM; t += 256) { sW1[t] = Wr1[t]; sW2[t] = Wr2[t]; }
    for (int t = threadIdx.x; t < HDIM * 96; t += 256) sW3[t] = Wr3[t];
    for (int t = threadIdx.x; t < GNOD * 289; t += 256) sA[t] = 0.f;
    __syncthreads();

    int n0 = blockIdx.x * GNOD;
    int nhi = min(n0 + GNOD, N);
    int lo = rowptr[n0];
    int hi = rowptr[nhi];

    for (int k = lo + (int)threadIdx.x; k < hi; k += 256) {
        int s = eS[k], t = eT[k];

        float dx = pos[3*t+0] - pos[3*s+0];
        float dy = pos[3*t+1] - pos[3*s+1];
        float dz = pos[3*t+2] - pos[3*s+2];
        float r  = sqrtf(dx*dx + dy*dy + dz*dz + 1e-12f);
        float inv_r = 1.0f / r;
        float ux = dx*inv_r, uy = dy*inv_r, uz = dz*inv_r;
        float u  = r / 5.0f;
        float u2 = u*u, u5 = u2*u2*u;
        float fcut = 1.0f - 21.0f*u5 + 35.0f*u5*u - 15.0f*u5*u2;

        float Rb[NBES];
        float coef = 0.632455532f * inv_r * fcut;
        #pragma unroll
        for (int kk = 0; kk < NBES; ++kk)
            Rb[kk] = coef * __sinf((float)(kk+1) * 0.628318531f * r);

        const float s3 = 1.73205081f, s5 = 2.23606798f, s15 = 3.87298335f;
        float sh1 = s3 * ux, sh2 = s3 * uy, sh3 = s3 * uz;
        float sh4 = s15 * ux * uy, sh5 = s15 * uy * uz;
        float sh6 = 0.5f * s5 * (3.0f * uz * uz - 1.0f);
        float sh7 = s15 * ux * uz;
        float sh8 = 0.5f * s15 * (ux * ux - uy * uy);

        float a[HDIM], b[HDIM];
        // L1: 8 -> 64, silu
        #pragma unroll
        for (int j0 = 0; j0 < HDIM; j0 += 4) {
            float q0=0.f,q1=0.f,q2=0.f,q3=0.f;
            #pragma unroll
            for (int kk = 0; kk < NBES; ++kk) {
                float av = Rb[kk];
                const float* wp = sW0 + kk * HDIM + j0;
                q0 += av*wp[0]; q1 += av*wp[1]; q2 += av*wp[2]; q3 += av*wp[3];
            }
            a[j0]=silu_f(q0); a[j0+1]=silu_f(q1); a[j0+2]=silu_f(q2); a[j0+3]=silu_f(q3);
        }
        // L2: 64 -> 64, silu
        #pragma unroll
        for (int j0 = 0; j0 < HDIM; j0 += 4) {
            float q0=0.f,q1=0.f,q2=0.f,q3=0.f;
            #pragma unroll
            for (int kk = 0; kk < HDIM; ++kk) {
                float av = a[kk];
                const float* wp = sW1 + kk * HDIM + j0;
                q0 += av*wp[0]; q1 += av*wp[1]; q2 += av*wp[2]; q3 += av*wp[3];
            }
            b[j0]=silu_f(q0); b[j0+1]=silu_f(q1); b[j0+2]=silu_f(q2); b[j0+3]=silu_f(q3);
        }
        // L3: 64 -> 64, silu
        #pragma unroll
        for (int j0 = 0; j0 < HDIM; j0 += 4) {
            float q0=0.f,q1=0.f,q2=0.f,q3=0.f;
            #pragma unroll
            for (int kk = 0; kk < HDIM; ++kk) {
                float av = b[kk];
                const float* wp = sW2 + kk * HDIM + j0;
                q0 += av*wp[0]; q1 += av*wp[1]; q2 += av*wp[2]; q3 += av*wp[3];
            }
            a[j0]=silu_f(q0); a[j0+1]=silu_f(q1); a[j0+2]=silu_f(q2); a[j0+3]=silu_f(q3);
        }
        // sender features
        float h1r[Cdim];
        #pragma unroll
        for (int c4 = 0; c4 < 8; ++c4) {
            float4 v = *(const float4*)(h1 + (size_t)s * Cdim + c4 * 4);
            h1r[c4*4+0] = v.x; h1r[c4*4+1] = v.y; h1r[c4*4+2] = v.z; h1r[c4*4+3] = v.w;
        }
        // L4 (64 -> 96) fused with LDS accumulate
        float* Ar = sA + (t - n0) * 289;
        #pragma unroll
        for (int c0 = 0; c0 < Cdim; c0 += 4) {
            float w0[4] = {0,0,0,0}, w1v[4] = {0,0,0,0}, w2v[4] = {0,0,0,0};
            #pragma unroll
            for (int kk = 0; kk < HDIM; ++kk) {
                float av = a[kk];
                const float* wp = sW3 + kk * 96;
                #pragma unroll
                for (int j = 0; j < 4; ++j) {
                    w0[j]  += av * wp[c0 + j];
                    w1v[j] += av * wp[32 + c0 + j];
                    w2v[j] += av * wp[64 + c0 + j];
                }
            }
            #pragma unroll
            for (int j = 0; j < 4; ++j) {
                int c = c0 + j;
                float m0 = h1r[c] * w0[j];
                float m1 = h1r[c] * w1v[j];
                float m2 = h1r[c] * w2v[j];
                atomicAdd(&Ar[0*Cdim + c], m0);          // sh0 = 1
                atomicAdd(&Ar[1*Cdim + c], sh1 * m1);
                atomicAdd(&Ar[2*Cdim + c], sh2 * m1);
                atomicAdd(&Ar[3*Cdim + c], sh3 * m1);
                atomicAdd(&Ar[4*Cdim + c], sh4 * m2);
                atomicAdd(&Ar[5*Cdim + c], sh5 * m2);
                atomicAdd(&Ar[6*Cdim + c], sh6 * m2);
                atomicAdd(&Ar[7*Cdim + c], sh7 * m2);
                atomicAdd(&Ar[8*Cdim + c], sh8 * m2);
            }
        }
    }
    __syncthreads();
    // write A rows (raw sums; downstream kernels divide by 16)
    int nloc_cnt = nhi - n0;
    for (int t = threadIdx.x; t < nloc_cnt * 288; t += 256) {
        int nl = t / 288, off = t - nl * 288;
        feats[(size_t)(n0 + nl) * 576 + 288 + off] = sA[nl * 289 + off];
    }
}

// ---------------- out[n,m,:] = (A[n,m,:]/16) @ Wprod[L[m]]  for m=1..8 ----------------
__global__ __launch_bounds__(256)
void k_out_m(float* AO, const float* __restrict__ Wprod, int N, int outslot)
{
    __shared__ float sW[3 * Cdim * Cdim];
    for (int t = threadIdx.x; t < 3 * Cdim * Cdim; t += 256) sW[t] = Wprod[t];
    __syncthreads();
    int t = blockIdx.x * blockDim.x + threadIdx.x;
    if (t >= N * 8) return;
    int m = (t & 7) + 1;
    int n = t >> 3;
    int l = (m <= 3) ? 1 : 2;
    const float* Ar = AO + (size_t)n * 576 + 288 + m * Cdim;
    float Av[Cdim];
    #pragma unroll
    for (int c4 = 0; c4 < 8; ++c4) {
        float4 v = *(const float4*)(Ar + c4 * 4);
        Av[c4*4+0]=v.x*0.0625f; Av[c4*4+1]=v.y*0.0625f;
        Av[c4*4+2]=v.z*0.0625f; Av[c4*4+3]=v.w*0.0625f;
    }
    float acc[Cdim];
    #pragma unroll
    for (int d = 0; d < Cdim; ++d) acc[d] = 0.f;
    const float* wbase = sW + l * Cdim * Cdim;
    #pragma unroll
    for (int c = 0; c < Cdim; ++c) {
        float av = Av[c];
        #pragma unroll
        for (int d = 0; d < Cdim; ++d) acc[d] += av * wbase[c * Cdim + d];
    }
    float* o = AO + (size_t)n * 576 + outslot + m * Cdim;
    #pragma unroll
    for (int d4 = 0; d4 < 8; ++d4)
        *(float4*)(o + d4 * 4) = make_float4(acc[d4*4], acc[d4*4+1], acc[d4*4+2], acc[d4*4+3]);
}

// ---------------- per-node scalar channel: out0 + poly + sc, energy, h update ----------------
template<int ITER>
__global__ __launch_bounds__(256)
void k_node_scalar(float* AO, const float* h, const int* __restrict__ elem,
                   const float* __restrict__ Wprod0, const float* __restrict__ Wsc,
                   const float* __restrict__ Wp, const float* __restrict__ w_ro1,
                   const float* __restrict__ W_m1, const float* __restrict__ w_m2,
                   float* h_next, float* __restrict__ energy, int N, int outslot)
{
    __shared__ float sW0[Cdim * Cdim];
    __shared__ float sM1[Cdim * 16];
    __shared__ float sm2[16];
    __shared__ float sro[Cdim];
    for (int t = threadIdx.x; t < Cdim * Cdim; t += 256) sW0[t] = Wprod0[t];
    for (int t = threadIdx.x; t < Cdim * 16; t += 256) sM1[t] = W_m1[t];
    if (threadIdx.x < 16) sm2[threadIdx.x] = w_m2[threadIdx.x];
    if (threadIdx.x < Cdim) sro[threadIdx.x] = w_ro1[threadIdx.x];
    __syncthreads();
    int n = blockIdx.x * blockDim.x + threadIdx.x;
    if (n >= N) return;
    int el = elem[n];
    const float* Ar = AO + (size_t)n * 576 + 288;
    float A0[Cdim], hv[Cdim];
    #pragma unroll
    for (int c4 = 0; c4 < 8; ++c4) {
        float4 v = *(const float4*)(Ar + c4 * 4);
        A0[c4*4+0]=v.x*0.0625f; A0[c4*4+1]=v.y*0.0625f;
        A0[c4*4+2]=v.z*0.0625f; A0[c4*4+3]=v.w*0.0625f;
        float4 w = *(const float4*)(h + (size_t)n * Cdim + c4 * 4);
        hv[c4*4+0]=w.x; hv[c4*4+1]=w.y; hv[c4*4+2]=w.z; hv[c4*4+3]=w.w;
    }
    float hs[Cdim];
    #pragma unroll
    for (int d = 0; d < Cdim; ++d) hs[d] = 0.f;
    // out0 = A0 @ Wprod[0]
    #pragma unroll
    for (int c = 0; c < Cdim; ++c) {
        float av = A0[c];
        #pragma unroll
        for (int d = 0; d < Cdim; ++d) hs[d] += av * sW0[c * Cdim + d];
    }
    // sc = h @ Wsc[elem]
    const float* Ws = Wsc + (size_t)el * Cdim * Cdim;
    #pragma unroll
    for (int c = 0; c < Cdim; ++c) {
        float hc = hv[c];
        #pragma unroll
        for (int d = 0; d < Cdim; ++d) hs[d] += hc * Ws[c * Cdim + d];
    }
    // poly
    const float* wp0 = Wp + 0 * (ZDIM * Cdim) + el * Cdim;
    const float* wp1 = Wp + 1 * (ZDIM * Cdim) + el * Cdim;
    const float* wp2 = Wp + 2 * (ZDIM * Cdim) + el * Cdim;
    #pragma unroll
    for (int d = 0; d < Cdim; ++d) {
        float A = A0[d], A2 = A * A;
        hs[d] += wp0[d] * A + wp1[d] * A2 + wp2[d] * (A2 * A);
    }
    // energy readout
    float eadd;
    if (ITER == 0) {
        float acc = 0.f;
        #pragma unroll
        for (int d = 0; d < Cdim; ++d) acc += hs[d] * sro[d];
        eadd = acc;
    } else {
        float acc = 0.f;
        #pragma unroll
        for (int j = 0; j < 16; ++j) {
            float tj = 0.f;
            #pragma unroll
            for (int d = 0; d < Cdim; ++d) tj += hs[d] * sM1[d * 16 + j];
            acc += silu_f(tj) * sm2[j];
        }
        eadd = acc;
    }
    energy[n] += eadd;
    float* o = AO + (size_t)n * 576 + outslot;
    #pragma unroll
    for (int d4 = 0; d4 < 8; ++d4)
        *(float4*)(o + d4 * 4) = make_float4(hs[d4*4], hs[d4*4+1], hs[d4*4+2], hs[d4*4+3]);
    if (ITER == 0) {
        #pragma unroll
        for (int d4 = 0; d4 < 8; ++d4)
            *(float4*)(h_next + (size_t)n * Cdim + d4 * 4) =
                make_float4(hs[d4*4], hs[d4*4+1], hs[d4*4+2], hs[d4*4+3]);
    }
}

extern "C" void kernel_launch(void* const* d_in, const int* in_sizes, int n_in,
                              void* d_out, int out_size, void* d_ws, size_t ws_size,
                              hipStream_t stream)
{
    const float* attrs   = (const float*)d_in[0];
    const float* pos     = (const float*)d_in[1];
    const int*   snd     = (const int*)d_in[2];
    const int*   rcv     = (const int*)d_in[3];
    const float* W_embed = (const float*)d_in[4];
    const float* atomE   = (const float*)d_in[5];
    const float* Wr0     = (const float*)d_in[6];
    const float* Wr1     = (const float*)d_in[7];
    const float* Wr2     = (const float*)d_in[8];
    const float* Wr3     = (const float*)d_in[9];
    const float* Wlin    = (const float*)d_in[10];
    const float* Wsc     = (const float*)d_in[11];
    const float* Wprod   = (const float*)d_in[12];
    const float* Wp      = (const float*)d_in[13];
    const float* w_ro1   = (const float*)d_in[14];
    const float* W_m1    = (const float*)d_in[15];
    const float* w_m2    = (const float*)d_in[16];

    const int N = in_sizes[1] / 3;
    const int E = in_sizes[2];

    float* energy = (float*)d_out;
    float* feats  = (float*)d_out + N;   // N x 576; A lives in feats1 slot (offset 288)

    char* ws = (char*)d_ws;
    size_t off = 0;
    auto alloc = [&](size_t bytes) { void* p = ws + off; off = (off + bytes + 255) & ~(size_t)255; return p; };
    int* deg    = (int*)alloc((size_t)N * 4);
    int* cursor = (int*)alloc((size_t)N * 4);
    int* rowptr = (int*)alloc((size_t)(N + 1) * 4);
    int* eS     = (int*)alloc((size_t)E * 4);
    int* eT     = (int*)alloc((size_t)E * 4);
    int* elem   = (int*)alloc((size_t)N * 4);
    float* h    = (float*)alloc((size_t)N * Cdim * 4);
    float* h1   = (float*)alloc((size_t)N * Cdim * 4);

    k_node_init<<<(N + 255)/256, 256, 0, stream>>>(attrs, W_embed, atomE, elem, h, energy, deg, N);
    k_edge_zbl<<<(E + 255)/256, 256, 0, stream>>>(pos, snd, rcv, elem, energy, deg, E);
    k_scan<<<1, 1024, 0, stream>>>(deg, rowptr, cursor, N);
    k_place<<<(E + 255)/256, 256, 0, stream>>>(pos, snd, rcv, cursor, eS, eT, E);

    const int NBLK = (N + GNOD - 1) / GNOD;
    for (int i = 0; i < 2; ++i) {
        k_h1<<<(N + 255)/256, 256, 0, stream>>>(h, Wlin + i * Cdim * Cdim, h1, N);
        k_gather<<<NBLK, 256, 0, stream>>>(rowptr, eS, eT, pos, h1,
            Wr0 + i * NBES * HDIM, Wr1 + i * HDIM * HDIM,
            Wr2 + i * HDIM * HDIM, Wr3 + i * HDIM * 96, feats, N);
        k_out_m<<<(N*8 + 255)/256, 256, 0, stream>>>(feats, Wprod + i * 3 * Cdim * Cdim,
                                                     N, (i == 0) ? 0 : 288);
        if (i == 0)
            k_node_scalar<0><<<(N + 255)/256, 256, 0, stream>>>(feats, h, elem,
                Wprod + 0 * 3072, Wsc + 0 * 10240, Wp + 0 * 960,
                w_ro1, W_m1, w_m2, h, energy, N, 0);
        else
            k_node_scalar<1><<<(N + 255)/256, 256, 0, stream>>>(feats, h, elem,
                Wprod + 1 * 3072, Wsc + 1 * 10240, Wp + 1 * 960,
                w_ro1, W_m1, w_m2, h, energy, N, 288);
    }
}

// Round 3
// 1286.721 us; speedup vs baseline: 5.3355x; 1.7934x over previous
//
#include <hip/hip_runtime.h>
#include <math.h>

static constexpr int Cdim = 32;   // C
static constexpr int NBES = 8;    // NB
static constexpr int HDIM = 64;   // H
static constexpr int ZDIM = 10;   // Z
static constexpr int GNOD = 49;   // nodes per gather block

typedef _Float16 half8 __attribute__((ext_vector_type(8)));
typedef float floatx4 __attribute__((ext_vector_type(4)));

__device__ __forceinline__ float silu_f(float x) {
    return x / (1.0f + __expf(-x));
}

// ---------------- node init: elem, h=W_embed[elem] (into feats m=0 slot), energy, deg=0 ----------------
__global__ __launch_bounds__(256)
void k_node_init(const float* __restrict__ attrs, const float* __restrict__ W_embed,
                 const float* __restrict__ atomE, int* __restrict__ elem,
                 float* hOut /* feats base, stride 576 */, float* __restrict__ energy,
                 int* __restrict__ deg, int N)
{
    int n = blockIdx.x * blockDim.x + threadIdx.x;
    if (n >= N) return;
    int e = 0; float best = -1.0f;
    #pragma unroll
    for (int z = 0; z < ZDIM; ++z) {
        float v = attrs[n * ZDIM + z];
        if (v > best) { best = v; e = z; }
    }
    elem[n] = e;
    #pragma unroll
    for (int c = 0; c < Cdim; ++c) hOut[(size_t)n * 576 + c] = W_embed[e * Cdim + c];
    energy[n] = atomE[e];
    deg[n] = 0;
}

// ---------------- ZBL pair energy + per-receiver degree count ----------------
__global__ __launch_bounds__(256)
void k_edge_zbl(const float* __restrict__ pos, const int* __restrict__ snd,
                const int* __restrict__ rcv, const int* __restrict__ elem,
                float* __restrict__ energy, int* __restrict__ deg, int E)
{
    int e = blockIdx.x * blockDim.x + threadIdx.x;
    if (e >= E) return;
    int s = snd[e], t = rcv[e];
    float dx = pos[3*t+0] - pos[3*s+0];
    float dy = pos[3*t+1] - pos[3*s+1];
    float dz = pos[3*t+2] - pos[3*s+2];
    float r  = sqrtf(dx*dx + dy*dy + dz*dz + 1e-12f);
    float u  = r / 5.0f;
    if (!(u < 1.0f)) return;
    float u2 = u*u, u5 = u2*u2*u;
    float fcut = 1.0f - 21.0f*u5 + 35.0f*u5*u - 15.0f*u5*u2;
    float zi = (float)(elem[s] + 1);
    float zj = (float)(elem[t] + 1);
    float a  = 0.4685f / (powf(zi, 0.23f) + powf(zj, 0.23f));
    float xx = r / a;
    float phi = 0.1818f*expf(-3.2f*xx) + 0.5099f*expf(-0.9423f*xx)
              + 0.2802f*expf(-0.4029f*xx) + 0.02817f*expf(-0.2016f*xx);
    float v = 14.3996f * zi * zj / r * phi * fcut;
    atomicAdd(&energy[t], 0.5f * v);
    atomicAdd(&deg[t], 1);
}

// ---------------- single-block exclusive scan ----------------
__global__ __launch_bounds__(1024)
void k_scan(const int* __restrict__ deg, int* __restrict__ rowptr,
            int* __restrict__ cursor, int N)
{
    __shared__ int wsum[16];
    __shared__ int chunk_base;
    int tid = threadIdx.x;
    int lane = tid & 63, w = tid >> 6;
    if (tid == 0) chunk_base = 0;
    __syncthreads();
    for (int base = 0; base < N; base += 1024) {
        int i = base + tid;
        int v = (i < N) ? deg[i] : 0;
        int s = v;
        #pragma unroll
        for (int d = 1; d < 64; d <<= 1) {
            int u = __shfl_up(s, d);
            if (lane >= d) s += u;
        }
        if (lane == 63) wsum[w] = s;
        __syncthreads();
        if (w == 0 && lane < 16) {
            int x = wsum[lane];
            #pragma unroll
            for (int d = 1; d < 16; d <<= 1) {
                int u = __shfl_up(x, d);
                if (lane >= d) x += u;
            }
            wsum[lane] = x;
        }
        __syncthreads();
        int wave_off = (w == 0) ? 0 : wsum[w - 1];
        int excl = chunk_base + wave_off + (s - v);
        if (i < N) { rowptr[i] = excl; cursor[i] = excl; }
        int total = wsum[15];
        __syncthreads();
        if (tid == 0) chunk_base += total;
        __syncthreads();
    }
    if (tid == 0) rowptr[N] = chunk_base;
}

// ---------------- place active edges into CSR slots ----------------
__global__ __launch_bounds__(256)
void k_place(const float* __restrict__ pos, const int* __restrict__ snd,
             const int* __restrict__ rcv, int* __restrict__ cursor,
             int* __restrict__ eS, int* __restrict__ eT, int E)
{
    int e = blockIdx.x * blockDim.x + threadIdx.x;
    if (e >= E) return;
    int s = snd[e], t = rcv[e];
    float dx = pos[3*t+0] - pos[3*s+0];
    float dy = pos[3*t+1] - pos[3*s+1];
    float dz = pos[3*t+2] - pos[3*s+2];
    float r  = sqrtf(dx*dx + dy*dy + dz*dz + 1e-12f);
    if (!(r / 5.0f < 1.0f)) return;
    int slot = atomicAdd(&cursor[t], 1);
    eS[slot] = s;
    eT[slot] = t;
}

// ---------------- h1 = h @ Wlin[i]   (h lives at feats[:,0:32], stride 576) ----------------
__global__ __launch_bounds__(256)
void k_h1(const float* h, const float* __restrict__ Wlin,
          float* __restrict__ h1, int N)
{
    __shared__ float sW[Cdim * Cdim];
    for (int t = threadIdx.x; t < Cdim * Cdim; t += 256) sW[t] = Wlin[t];
    __syncthreads();
    int n = blockIdx.x * blockDim.x + threadIdx.x;
    if (n >= N) return;
    float hv[Cdim];
    #pragma unroll
    for (int c4 = 0; c4 < 8; ++c4) {
        float4 v = *(const float4*)(h + (size_t)n * 576 + c4 * 4);
        hv[c4*4+0] = v.x; hv[c4*4+1] = v.y; hv[c4*4+2] = v.z; hv[c4*4+3] = v.w;
    }
    float acc[Cdim];
    #pragma unroll
    for (int d = 0; d < Cdim; ++d) acc[d] = 0.f;
    #pragma unroll
    for (int c = 0; c < Cdim; ++c) {
        float hc = hv[c];
        #pragma unroll
        for (int d = 0; d < Cdim; ++d) acc[d] += hc * sW[c * Cdim + d];
    }
    #pragma unroll
    for (int d4 = 0; d4 < 8; ++d4)
        *(float4*)(h1 + (size_t)n * Cdim + d4 * 4) =
            make_float4(acc[d4*4], acc[d4*4+1], acc[d4*4+2], acc[d4*4+3]);
}

// ---------------- radial MLP via f16 MFMA: w_out[k][96] for each CSR slot k ----------------
__global__ __launch_bounds__(256)
void k_mlp(const int* __restrict__ eS, const int* __restrict__ eT,
           const float* __restrict__ pos,
           const float* __restrict__ W0, const float* __restrict__ W1,
           const float* __restrict__ W2, const float* __restrict__ W3,
           const int* __restrict__ eactp, _Float16* __restrict__ w_out)
{
    // transposed fp16 weights, XOR-swizzled rows (out-channel = row)
    __shared__ __align__(16) _Float16 sWt0[64*32];   // 64B rows, swz (n&3)<<4
    __shared__ __align__(16) _Float16 sWt1[64*64];   // 128B rows, swz (n&7)<<4
    __shared__ __align__(16) _Float16 sWt2[64*64];
    __shared__ __align__(16) _Float16 sWt3[96*64];
    __shared__ __align__(16) _Float16 sAct[4][64*64];  // per-wave [64 edge][64 feat]

    for (int idx = threadIdx.x; idx < 64*32; idx += 256) {
        int n = idx >> 5, k = idx & 31;
        float v = (k < NBES) ? W0[k*64 + n] : 0.f;
        *(_Float16*)((char*)sWt0 + n*64 + ((k*2) ^ ((n&3)<<4))) = (_Float16)v;
    }
    for (int idx = threadIdx.x; idx < 64*64; idx += 256) {
        int k = idx >> 6, n = idx & 63;
        int byo = n*128 + ((k*2) ^ ((n&7)<<4));
        *(_Float16*)((char*)sWt1 + byo) = (_Float16)W1[idx];
        *(_Float16*)((char*)sWt2 + byo) = (_Float16)W2[idx];
    }
    for (int idx = threadIdx.x; idx < 64*96; idx += 256) {
        int k = idx / 96, n = idx - k*96;
        *(_Float16*)((char*)sWt3 + n*128 + ((k*2) ^ ((n&7)<<4))) = (_Float16)W3[idx];
    }
    __syncthreads();

    const int wid = threadIdx.x >> 6, lane = threadIdx.x & 63;
    const int l15 = lane & 15, lh = lane >> 4;
    const int Eact = *eactp;
    char* actc = (char*)sAct[wid];

    for (int c0 = (blockIdx.x*4 + wid)*64; c0 < Eact; c0 += gridDim.x*256) {
        int k = c0 + lane;
        bool ok = k < Eact;
        int kk = ok ? k : 0;
        int s = eS[kk], t = eT[kk];
        float dx = pos[3*t+0]-pos[3*s+0];
        float dy = pos[3*t+1]-pos[3*s+1];
        float dz = pos[3*t+2]-pos[3*s+2];
        float r  = sqrtf(dx*dx + dy*dy + dz*dz + 1e-12f);
        float inv_r = 1.0f / r;
        float u  = r / 5.0f;
        float u2 = u*u, u5 = u2*u2*u;
        float fcut = 1.0f - 21.0f*u5 + 35.0f*u5*u - 15.0f*u5*u2;
        float coef = 0.632455532f * inv_r * fcut;
        if (!ok) coef = 0.f;
        half8 rv;
        #pragma unroll
        for (int j = 0; j < NBES; ++j)
            rv[j] = (_Float16)(coef * __sinf((float)(j+1) * 0.628318531f * r));
        // write R row (k 0..7) + zero k 8..31
        {
            int sw = (lane & 7) << 4;
            half8 zz = {};
            *(half8*)(actc + lane*128 + ( 0 ^ sw)) = rv;
            *(half8*)(actc + lane*128 + (16 ^ sw)) = zz;
            *(half8*)(actc + lane*128 + (32 ^ sw)) = zz;
            *(half8*)(actc + lane*128 + (48 ^ sw)) = zz;
        }
        __builtin_amdgcn_sched_barrier(0);

        // ---- L1: [64x32(pad)] @ [32x64] ----
        {
            half8 b[4];
            #pragma unroll
            for (int nt = 0; nt < 4; ++nt) {
                int n = nt*16 + l15;
                b[nt] = *(half8*)((char*)sWt0 + n*64 + ((lh*16) ^ ((n&3)<<4)));
            }
            #pragma unroll
            for (int mt = 0; mt < 4; ++mt) {
                int rr = mt*16 + l15;
                half8 a = *(half8*)(actc + rr*128 + ((lh*16) ^ ((rr&7)<<4)));
                floatx4 d[4];
                #pragma unroll
                for (int nt = 0; nt < 4; ++nt) {
                    floatx4 z = {0.f,0.f,0.f,0.f};
                    d[nt] = __builtin_amdgcn_mfma_f32_16x16x32_f16(a, b[nt], z, 0,0,0);
                }
                #pragma unroll
                for (int nt = 0; nt < 4; ++nt)
                #pragma unroll
                for (int j = 0; j < 4; ++j) {
                    int wr = mt*16 + lh*4 + j;
                    *(_Float16*)(actc + wr*128 + ((((nt*16+l15)*2)) ^ ((wr&7)<<4))) =
                        (_Float16)silu_f(d[nt][j]);
                }
            }
        }
        __builtin_amdgcn_sched_barrier(0);

        // ---- L2, L3: [64x64] @ [64x64] ----
        const _Float16* Wl[2] = { sWt1, sWt2 };
        #pragma unroll
        for (int layer = 0; layer < 2; ++layer) {
            const char* wc = (const char*)Wl[layer];
            half8 b[4][2];
            #pragma unroll
            for (int nt = 0; nt < 4; ++nt)
            #pragma unroll
            for (int ks = 0; ks < 2; ++ks) {
                int n = nt*16 + l15;
                b[nt][ks] = *(half8*)(wc + n*128 + ((ks*64 + lh*16) ^ ((n&7)<<4)));
            }
            #pragma unroll
            for (int mt = 0; mt < 4; ++mt) {
                int rr = mt*16 + l15;
                half8 a0 = *(half8*)(actc + rr*128 + ((      lh*16) ^ ((rr&7)<<4)));
                half8 a1 = *(half8*)(actc + rr*128 + ((64 + lh*16) ^ ((rr&7)<<4)));
                floatx4 d[4];
                #pragma unroll
                for (int nt = 0; nt < 4; ++nt) {
                    floatx4 z = {0.f,0.f,0.f,0.f};
                    z = __builtin_amdgcn_mfma_f32_16x16x32_f16(a0, b[nt][0], z, 0,0,0);
                    d[nt] = __builtin_amdgcn_mfma_f32_16x16x32_f16(a1, b[nt][1], z, 0,0,0);
                }
                #pragma unroll
                for (int nt = 0; nt < 4; ++nt)
                #pragma unroll
                for (int j = 0; j < 4; ++j) {
                    int wr = mt*16 + lh*4 + j;
                    *(_Float16*)(actc + wr*128 + ((((nt*16+l15)*2)) ^ ((wr&7)<<4))) =
                        (_Float16)silu_f(d[nt][j]);
                }
            }
            __builtin_amdgcn_sched_barrier(0);
        }

        // ---- L4: [64x64] @ [64x96] -> w_out ----
        {
            half8 b[6][2];
            #pragma unroll
            for (int nt = 0; nt < 6; ++nt)
            #pragma unroll
            for (int ks = 0; ks < 2; ++ks) {
                int n = nt*16 + l15;
                b[nt][ks] = *(half8*)((char*)sWt3 + n*128 + ((ks*64 + lh*16) ^ ((n&7)<<4)));
            }
            #pragma unroll
            for (int mt = 0; mt < 4; ++mt) {
                int rr = mt*16 + l15;
                half8 a0 = *(half8*)(actc + rr*128 + ((      lh*16) ^ ((rr&7)<<4)));
                half8 a1 = *(half8*)(actc + rr*128 + ((64 + lh*16) ^ ((rr&7)<<4)));
                #pragma unroll
                for (int nt = 0; nt < 6; ++nt) {
                    floatx4 z = {0.f,0.f,0.f,0.f};
                    z = __builtin_amdgcn_mfma_f32_16x16x32_f16(a0, b[nt][0], z, 0,0,0);
                    floatx4 d = __builtin_amdgcn_mfma_f32_16x16x32_f16(a1, b[nt][1], z, 0,0,0);
                    #pragma unroll
                    for (int j = 0; j < 4; ++j) {
                        int e = c0 + mt*16 + lh*4 + j;
                        if (e < Eact)
                            w_out[(size_t)e*96 + nt*16 + l15] = (_Float16)d[j];
                    }
                }
            }
        }
        __builtin_amdgcn_sched_barrier(0);
    }
}

// ---------------- gather: read w_out, scatter messages into per-node LDS A ----------------
__global__ __launch_bounds__(256)
void k_gather(const int* __restrict__ rowptr, const int* __restrict__ eS,
              const int* __restrict__ eT, const float* __restrict__ pos,
              const float* __restrict__ h1, const _Float16* __restrict__ w_out,
              float* __restrict__ feats, int N)
{
    __shared__ float sA[GNOD * 289];
    for (int t = threadIdx.x; t < GNOD * 289; t += 256) sA[t] = 0.f;
    __syncthreads();

    int n0 = blockIdx.x * GNOD;
    int nhi = min(n0 + GNOD, N);
    int lo = rowptr[n0];
    int hi = rowptr[nhi];

    for (int k = lo + (int)threadIdx.x; k < hi; k += 256) {
        int s = eS[k], t = eT[k];
        float dx = pos[3*t+0] - pos[3*s+0];
        float dy = pos[3*t+1] - pos[3*s+1];
        float dz = pos[3*t+2] - pos[3*s+2];
        float r  = sqrtf(dx*dx + dy*dy + dz*dz + 1e-12f);
        float inv_r = 1.0f / r;
        float ux = dx*inv_r, uy = dy*inv_r, uz = dz*inv_r;
        const float s3 = 1.73205081f, s5 = 2.23606798f, s15 = 3.87298335f;
        float sh1 = s3 * ux, sh2 = s3 * uy, sh3 = s3 * uz;
        float sh4 = s15 * ux * uy, sh5 = s15 * uy * uz;
        float sh6 = 0.5f * s5 * (3.0f * uz * uz - 1.0f);
        float sh7 = s15 * ux * uz;
        float sh8 = 0.5f * s15 * (ux * ux - uy * uy);

        const _Float16* wp = w_out + (size_t)k * 96;
        const float* hp = h1 + (size_t)s * Cdim;
        float* Ar = sA + (t - n0) * 289;

        #pragma unroll
        for (int g = 0; g < 4; ++g) {
            half8 w0v = *(const half8*)(wp + g*8);
            half8 w1v = *(const half8*)(wp + 32 + g*8);
            half8 w2v = *(const half8*)(wp + 64 + g*8);
            float hbuf[8];
            *(float4*)(hbuf)     = *(const float4*)(hp + g*8);
            *(float4*)(hbuf + 4) = *(const float4*)(hp + g*8 + 4);
            #pragma unroll
            for (int j = 0; j < 8; ++j) {
                int c = g*8 + j;
                float hc = hbuf[j];
                float m0 = hc * (float)w0v[j];
                float m1 = hc * (float)w1v[j];
                float m2 = hc * (float)w2v[j];
                atomicAdd(&Ar[0*Cdim + c], m0);
                atomicAdd(&Ar[1*Cdim + c], sh1 * m1);
                atomicAdd(&Ar[2*Cdim + c], sh2 * m1);
                atomicAdd(&Ar[3*Cdim + c], sh3 * m1);
                atomicAdd(&Ar[4*Cdim + c], sh4 * m2);
                atomicAdd(&Ar[5*Cdim + c], sh5 * m2);
                atomicAdd(&Ar[6*Cdim + c], sh6 * m2);
                atomicAdd(&Ar[7*Cdim + c], sh7 * m2);
                atomicAdd(&Ar[8*Cdim + c], sh8 * m2);
            }
        }
    }
    __syncthreads();
    int nloc_cnt = nhi - n0;
    for (int t = threadIdx.x; t < nloc_cnt * 288; t += 256) {
        int nl = t / 288, off = t - nl * 288;
        feats[(size_t)(n0 + nl) * 576 + 288 + off] = sA[nl * 289 + off];
    }
}

// ---------------- out[n,m,:] = (A[n,m,:]/16) @ Wprod[L[m]]  for m=1..8 ----------------
__global__ __launch_bounds__(256)
void k_out_m(float* AO, const float* __restrict__ Wprod, int N, int outslot)
{
    __shared__ float sW[3 * Cdim * Cdim];
    for (int t = threadIdx.x; t < 3 * Cdim * Cdim; t += 256) sW[t] = Wprod[t];
    __syncthreads();
    int t = blockIdx.x * blockDim.x + threadIdx.x;
    if (t >= N * 8) return;
    int m = (t & 7) + 1;
    int n = t >> 3;
    int l = (m <= 3) ? 1 : 2;
    const float* Ar = AO + (size_t)n * 576 + 288 + m * Cdim;
    float Av[Cdim];
    #pragma unroll
    for (int c4 = 0; c4 < 8; ++c4) {
        float4 v = *(const float4*)(Ar + c4 * 4);
        Av[c4*4+0]=v.x*0.0625f; Av[c4*4+1]=v.y*0.0625f;
        Av[c4*4+2]=v.z*0.0625f; Av[c4*4+3]=v.w*0.0625f;
    }
    float acc[Cdim];
    #pragma unroll
    for (int d = 0; d < Cdim; ++d) acc[d] = 0.f;
    const float* wbase = sW + l * Cdim * Cdim;
    #pragma unroll
    for (int c = 0; c < Cdim; ++c) {
        float av = Av[c];
        #pragma unroll
        for (int d = 0; d < Cdim; ++d) acc[d] += av * wbase[c * Cdim + d];
    }
    float* o = AO + (size_t)n * 576 + outslot + m * Cdim;
    #pragma unroll
    for (int d4 = 0; d4 < 8; ++d4)
        *(float4*)(o + d4 * 4) = make_float4(acc[d4*4], acc[d4*4+1], acc[d4*4+2], acc[d4*4+3]);
}

// ---------------- per-node scalar channel ----------------
template<int ITER>
__global__ __launch_bounds__(256)
void k_node_scalar(float* AO, const float* h /* feats base, stride 576 */,
                   const int* __restrict__ elem,
                   const float* __restrict__ Wprod0, const float* __restrict__ Wsc,
                   const float* __restrict__ Wp, const float* __restrict__ w_ro1,
                   const float* __restrict__ W_m1, const float* __restrict__ w_m2,
                   float* __restrict__ energy, int N, int outslot)
{
    __shared__ float sW0[Cdim * Cdim];
    __shared__ float sM1[Cdim * 16];
    __shared__ float sm2[16];
    __shared__ float sro[Cdim];
    for (int t = threadIdx.x; t < Cdim * Cdim; t += 256) sW0[t] = Wprod0[t];
    for (int t = threadIdx.x; t < Cdim * 16; t += 256) sM1[t] = W_m1[t];
    if (threadIdx.x < 16) sm2[threadIdx.x] = w_m2[threadIdx.x];
    if (threadIdx.x < Cdim) sro[threadIdx.x] = w_ro1[threadIdx.x];
    __syncthreads();
    int n = blockIdx.x * blockDim.x + threadIdx.x;
    if (n >= N) return;
    int el = elem[n];
    const float* Ar = AO + (size_t)n * 576 + 288;
    float A0[Cdim], hv[Cdim];
    #pragma unroll
    for (int c4 = 0; c4 < 8; ++c4) {
        float4 v = *(const float4*)(Ar + c4 * 4);
        A0[c4*4+0]=v.x*0.0625f; A0[c4*4+1]=v.y*0.0625f;
        A0[c4*4+2]=v.z*0.0625f; A0[c4*4+3]=v.w*0.0625f;
        float4 w = *(const float4*)(h + (size_t)n * 576 + c4 * 4);
        hv[c4*4+0]=w.x; hv[c4*4+1]=w.y; hv[c4*4+2]=w.z; hv[c4*4+3]=w.w;
    }
    float hs[Cdim];
    #pragma unroll
    for (int d = 0; d < Cdim; ++d) hs[d] = 0.f;
    #pragma unroll
    for (int c = 0; c < Cdim; ++c) {
        float av = A0[c];
        #pragma unroll
        for (int d = 0; d < Cdim; ++d) hs[d] += av * sW0[c * Cdim + d];
    }
    const float* Ws = Wsc + (size_t)el * Cdim * Cdim;
    #pragma unroll
    for (int c = 0; c < Cdim; ++c) {
        float hc = hv[c];
        #pragma unroll
        for (int d = 0; d < Cdim; ++d) hs[d] += hc * Ws[c * Cdim + d];
    }
    const float* wp0 = Wp + 0 * (ZDIM * Cdim) + el * Cdim;
    const float* wp1 = Wp + 1 * (ZDIM * Cdim) + el * Cdim;
    const float* wp2 = Wp + 2 * (ZDIM * Cdim) + el * Cdim;
    #pragma unroll
    for (int d = 0; d < Cdim; ++d) {
        float A = A0[d], A2 = A * A;
        hs[d] += wp0[d] * A + wp1[d] * A2 + wp2[d] * (A2 * A);
    }
    float eadd;
    if (ITER == 0) {
        float acc = 0.f;
        #pragma unroll
        for (int d = 0; d < Cdim; ++d) acc += hs[d] * sro[d];
        eadd = acc;
    } else {
        float acc = 0.f;
        #pragma unroll
        for (int j = 0; j < 16; ++j) {
            float tj = 0.f;
            #pragma unroll
            for (int d = 0; d < Cdim; ++d) tj += hs[d] * sM1[d * 16 + j];
            acc += silu_f(tj) * sm2[j];
        }
        eadd = acc;
    }
    energy[n] += eadd;
    float* o = AO + (size_t)n * 576 + outslot;   // ITER 0: this is also the h slot
    #pragma unroll
    for (int d4 = 0; d4 < 8; ++d4)
        *(float4*)(o + d4 * 4) = make_float4(hs[d4*4], hs[d4*4+1], hs[d4*4+2], hs[d4*4+3]);
}

extern "C" void kernel_launch(void* const* d_in, const int* in_sizes, int n_in,
                              void* d_out, int out_size, void* d_ws, size_t ws_size,
                              hipStream_t stream)
{
    const float* attrs   = (const float*)d_in[0];
    const float* pos     = (const float*)d_in[1];
    const int*   snd     = (const int*)d_in[2];
    const int*   rcv     = (const int*)d_in[3];
    const float* W_embed = (const float*)d_in[4];
    const float* atomE   = (const float*)d_in[5];
    const float* Wr0     = (const float*)d_in[6];
    const float* Wr1     = (const float*)d_in[7];
    const float* Wr2     = (const float*)d_in[8];
    const float* Wr3     = (const float*)d_in[9];
    const float* Wlin    = (const float*)d_in[10];
    const float* Wsc     = (const float*)d_in[11];
    const float* Wprod   = (const float*)d_in[12];
    const float* Wp      = (const float*)d_in[13];
    const float* w_ro1   = (const float*)d_in[14];
    const float* W_m1    = (const float*)d_in[15];
    const float* w_m2    = (const float*)d_in[16];

    const int N = in_sizes[1] / 3;
    const int E = in_sizes[2];

    float* energy = (float*)d_out;
    float* feats  = (float*)d_out + N;   // N x 576; h aliases feats[:,0:32]; A in feats1 slot

    char* ws = (char*)d_ws;
    size_t off = 0;
    auto alloc = [&](size_t bytes) { void* p = ws + off; off = (off + bytes + 255) & ~(size_t)255; return p; };
    int* deg    = (int*)alloc((size_t)N * 4);
    int* cursor = (int*)alloc((size_t)N * 4);
    int* rowptr = (int*)alloc((size_t)(N + 1) * 4);
    int* eS     = (int*)alloc((size_t)E * 4);
    int* eT     = (int*)alloc((size_t)E * 4);
    int* elem   = (int*)alloc((size_t)N * 4);
    float* h1   = (float*)alloc((size_t)N * Cdim * 4);
    _Float16* w_out = (_Float16*)(ws + off);   // ~E_act*96*2B touched (~43 MB)

    k_node_init<<<(N + 255)/256, 256, 0, stream>>>(attrs, W_embed, atomE, elem, feats, energy, deg, N);
    k_edge_zbl<<<(E + 255)/256, 256, 0, stream>>>(pos, snd, rcv, elem, energy, deg, E);
    k_scan<<<1, 1024, 0, stream>>>(deg, rowptr, cursor, N);
    k_place<<<(E + 255)/256, 256, 0, stream>>>(pos, snd, rcv, cursor, eS, eT, E);

    const int NBLK = (N + GNOD - 1) / GNOD;
    for (int i = 0; i < 2; ++i) {
        k_h1<<<(N + 255)/256, 256, 0, stream>>>(feats, Wlin + i * Cdim * Cdim, h1, N);
        k_mlp<<<512, 256, 0, stream>>>(eS, eT, pos,
            Wr0 + i * NBES * HDIM, Wr1 + i * HDIM * HDIM,
            Wr2 + i * HDIM * HDIM, Wr3 + i * HDIM * 96,
            rowptr + N, w_out);
        k_gather<<<NBLK, 256, 0, stream>>>(rowptr, eS, eT, pos, h1, w_out, feats, N);
        k_out_m<<<(N*8 + 255)/256, 256, 0, stream>>>(feats, Wprod + i * 3 * Cdim * Cdim,
                                                     N, (i == 0) ? 0 : 288);
        if (i == 0)
            k_node_scalar<0><<<(N + 255)/256, 256, 0, stream>>>(feats, feats, elem,
                Wprod + 0 * 3072, Wsc + 0 * 10240, Wp + 0 * 960,
                w_ro1, W_m1, w_m2, energy, N, 0);
        else
            k_node_scalar<1><<<(N + 255)/256, 256, 0, stream>>>(feats, feats, elem,
                Wprod + 1 * 3072, Wsc + 1 * 10240, Wp + 1 * 960,
                w_ro1, W_m1, w_m2, energy, N, 288);
    }
}

// Round 4
// 441.407 us; speedup vs baseline: 15.5532x; 2.9150x over previous
//
#include <hip/hip_runtime.h>
#include <math.h>

static constexpr int Cdim = 32;   // C
static constexpr int NBES = 8;    // NB
static constexpr int HDIM = 64;   // H
static constexpr int ZDIM = 10;   // Z

typedef _Float16 half8 __attribute__((ext_vector_type(8)));
typedef _Float16 half4 __attribute__((ext_vector_type(4)));
typedef float floatx4 __attribute__((ext_vector_type(4)));

__device__ __forceinline__ float silu_f(float x) {
    return x / (1.0f + __expf(-x));
}

// ---------------- node init ----------------
__global__ __launch_bounds__(256)
void k_node_init(const float* __restrict__ attrs, const float* __restrict__ W_embed,
                 const float* __restrict__ atomE, int* __restrict__ elem,
                 float* hOut /* feats base, stride 576 */, float* __restrict__ energy,
                 int* __restrict__ deg, int N)
{
    int n = blockIdx.x * blockDim.x + threadIdx.x;
    if (n >= N) return;
    int e = 0; float best = -1.0f;
    #pragma unroll
    for (int z = 0; z < ZDIM; ++z) {
        float v = attrs[n * ZDIM + z];
        if (v > best) { best = v; e = z; }
    }
    elem[n] = e;
    #pragma unroll
    for (int c = 0; c < Cdim; ++c) hOut[(size_t)n * 576 + c] = W_embed[e * Cdim + c];
    energy[n] = atomE[e];
    deg[n] = 0;
}

// ---------------- ZBL pair energy + per-receiver degree count ----------------
__global__ __launch_bounds__(256)
void k_edge_zbl(const float* __restrict__ pos, const int* __restrict__ snd,
                const int* __restrict__ rcv, const int* __restrict__ elem,
                float* __restrict__ energy, int* __restrict__ deg, int E)
{
    int e = blockIdx.x * blockDim.x + threadIdx.x;
    if (e >= E) return;
    int s = snd[e], t = rcv[e];
    float dx = pos[3*t+0] - pos[3*s+0];
    float dy = pos[3*t+1] - pos[3*s+1];
    float dz = pos[3*t+2] - pos[3*s+2];
    float r  = sqrtf(dx*dx + dy*dy + dz*dz + 1e-12f);
    float u  = r / 5.0f;
    if (!(u < 1.0f)) return;
    float u2 = u*u, u5 = u2*u2*u;
    float fcut = 1.0f - 21.0f*u5 + 35.0f*u5*u - 15.0f*u5*u2;
    float zi = (float)(elem[s] + 1);
    float zj = (float)(elem[t] + 1);
    float a  = 0.4685f / (powf(zi, 0.23f) + powf(zj, 0.23f));
    float xx = r / a;
    float phi = 0.1818f*expf(-3.2f*xx) + 0.5099f*expf(-0.9423f*xx)
              + 0.2802f*expf(-0.4029f*xx) + 0.02817f*expf(-0.2016f*xx);
    float v = 14.3996f * zi * zj / r * phi * fcut;
    atomicAdd(&energy[t], 0.5f * v);
    atomicAdd(&deg[t], 1);
}

// ---------------- single-block exclusive scan ----------------
__global__ __launch_bounds__(1024)
void k_scan(const int* __restrict__ deg, int* __restrict__ rowptr,
            int* __restrict__ cursor, int N)
{
    __shared__ int wsum[16];
    __shared__ int chunk_base;
    int tid = threadIdx.x;
    int lane = tid & 63, w = tid >> 6;
    if (tid == 0) chunk_base = 0;
    __syncthreads();
    for (int base = 0; base < N; base += 1024) {
        int i = base + tid;
        int v = (i < N) ? deg[i] : 0;
        int s = v;
        #pragma unroll
        for (int d = 1; d < 64; d <<= 1) {
            int u = __shfl_up(s, d);
            if (lane >= d) s += u;
        }
        if (lane == 63) wsum[w] = s;
        __syncthreads();
        if (w == 0 && lane < 16) {
            int x = wsum[lane];
            #pragma unroll
            for (int d = 1; d < 16; d <<= 1) {
                int u = __shfl_up(x, d);
                if (lane >= d) x += u;
            }
            wsum[lane] = x;
        }
        __syncthreads();
        int wave_off = (w == 0) ? 0 : wsum[w - 1];
        int excl = chunk_base + wave_off + (s - v);
        if (i < N) { rowptr[i] = excl; cursor[i] = excl; }
        int total = wsum[15];
        __syncthreads();
        if (tid == 0) chunk_base += total;
        __syncthreads();
    }
    if (tid == 0) rowptr[N] = chunk_base;
}

// ---------------- place active edges into CSR slots ----------------
__global__ __launch_bounds__(256)
void k_place(const float* __restrict__ pos, const int* __restrict__ snd,
             const int* __restrict__ rcv, int* __restrict__ cursor,
             int* __restrict__ eS, int* __restrict__ eT, int E)
{
    int e = blockIdx.x * blockDim.x + threadIdx.x;
    if (e >= E) return;
    int s = snd[e], t = rcv[e];
    float dx = pos[3*t+0] - pos[3*s+0];
    float dy = pos[3*t+1] - pos[3*s+1];
    float dz = pos[3*t+2] - pos[3*s+2];
    float r  = sqrtf(dx*dx + dy*dy + dz*dz + 1e-12f);
    if (!(r / 5.0f < 1.0f)) return;
    int slot = atomicAdd(&cursor[t], 1);
    eS[slot] = s;
    eT[slot] = t;
}

// ---------------- h1 = h @ Wlin[i] ----------------
__global__ __launch_bounds__(256)
void k_h1(const float* h, const float* __restrict__ Wlin,
          float* __restrict__ h1, int N)
{
    __shared__ float sW[Cdim * Cdim];
    for (int t = threadIdx.x; t < Cdim * Cdim; t += 256) sW[t] = Wlin[t];
    __syncthreads();
    int n = blockIdx.x * blockDim.x + threadIdx.x;
    if (n >= N) return;
    float hv[Cdim];
    #pragma unroll
    for (int c4 = 0; c4 < 8; ++c4) {
        float4 v = *(const float4*)(h + (size_t)n * 576 + c4 * 4);
        hv[c4*4+0] = v.x; hv[c4*4+1] = v.y; hv[c4*4+2] = v.z; hv[c4*4+3] = v.w;
    }
    float acc[Cdim];
    #pragma unroll
    for (int d = 0; d < Cdim; ++d) acc[d] = 0.f;
    #pragma unroll
    for (int c = 0; c < Cdim; ++c) {
        float hc = hv[c];
        #pragma unroll
        for (int d = 0; d < Cdim; ++d) acc[d] += hc * sW[c * Cdim + d];
    }
    #pragma unroll
    for (int d4 = 0; d4 < 8; ++d4)
        *(float4*)(h1 + (size_t)n * Cdim + d4 * 4) =
            make_float4(acc[d4*4], acc[d4*4+1], acc[d4*4+2], acc[d4*4+3]);
}

// ---------------- radial MLP via f16 MFMA: w_out[k][96] for each CSR slot k ----------------
__global__ __launch_bounds__(256)
void k_mlp(const int* __restrict__ eS, const int* __restrict__ eT,
           const float* __restrict__ pos,
           const float* __restrict__ W0, const float* __restrict__ W1,
           const float* __restrict__ W2, const float* __restrict__ W3,
           const int* __restrict__ eactp, _Float16* __restrict__ w_out)
{
    __shared__ __align__(16) _Float16 sWt0[64*32];
    __shared__ __align__(16) _Float16 sWt1[64*64];
    __shared__ __align__(16) _Float16 sWt2[64*64];
    __shared__ __align__(16) _Float16 sWt3[96*64];
    __shared__ __align__(16) _Float16 sAct[4][64*64];

    for (int idx = threadIdx.x; idx < 64*32; idx += 256) {
        int n = idx >> 5, k = idx & 31;
        float v = (k < NBES) ? W0[k*64 + n] : 0.f;
        *(_Float16*)((char*)sWt0 + n*64 + ((k*2) ^ ((n&3)<<4))) = (_Float16)v;
    }
    for (int idx = threadIdx.x; idx < 64*64; idx += 256) {
        int k = idx >> 6, n = idx & 63;
        int byo = n*128 + ((k*2) ^ ((n&7)<<4));
        *(_Float16*)((char*)sWt1 + byo) = (_Float16)W1[idx];
        *(_Float16*)((char*)sWt2 + byo) = (_Float16)W2[idx];
    }
    for (int idx = threadIdx.x; idx < 64*96; idx += 256) {
        int k = idx / 96, n = idx - k*96;
        *(_Float16*)((char*)sWt3 + n*128 + ((k*2) ^ ((n&7)<<4))) = (_Float16)W3[idx];
    }
    __syncthreads();

    const int wid = threadIdx.x >> 6, lane = threadIdx.x & 63;
    const int l15 = lane & 15, lh = lane >> 4;
    const int Eact = *eactp;
    char* actc = (char*)sAct[wid];

    for (int c0 = (blockIdx.x*4 + wid)*64; c0 < Eact; c0 += gridDim.x*256) {
        int k = c0 + lane;
        bool ok = k < Eact;
        int kk = ok ? k : 0;
        int s = eS[kk], t = eT[kk];
        float dx = pos[3*t+0]-pos[3*s+0];
        float dy = pos[3*t+1]-pos[3*s+1];
        float dz = pos[3*t+2]-pos[3*s+2];
        float r  = sqrtf(dx*dx + dy*dy + dz*dz + 1e-12f);
        float inv_r = 1.0f / r;
        float u  = r / 5.0f;
        float u2 = u*u, u5 = u2*u2*u;
        float fcut = 1.0f - 21.0f*u5 + 35.0f*u5*u - 15.0f*u5*u2;
        float coef = 0.632455532f * inv_r * fcut;
        if (!ok) coef = 0.f;
        half8 rv;
        #pragma unroll
        for (int j = 0; j < NBES; ++j)
            rv[j] = (_Float16)(coef * __sinf((float)(j+1) * 0.628318531f * r));
        {
            int sw = (lane & 7) << 4;
            half8 zz = {};
            *(half8*)(actc + lane*128 + ( 0 ^ sw)) = rv;
            *(half8*)(actc + lane*128 + (16 ^ sw)) = zz;
            *(half8*)(actc + lane*128 + (32 ^ sw)) = zz;
            *(half8*)(actc + lane*128 + (48 ^ sw)) = zz;
        }
        __builtin_amdgcn_sched_barrier(0);

        // ---- L1 ----
        {
            half8 b[4];
            #pragma unroll
            for (int nt = 0; nt < 4; ++nt) {
                int n = nt*16 + l15;
                b[nt] = *(half8*)((char*)sWt0 + n*64 + ((lh*16) ^ ((n&3)<<4)));
            }
            #pragma unroll
            for (int mt = 0; mt < 4; ++mt) {
                int rr = mt*16 + l15;
                half8 a = *(half8*)(actc + rr*128 + ((lh*16) ^ ((rr&7)<<4)));
                floatx4 d[4];
                #pragma unroll
                for (int nt = 0; nt < 4; ++nt) {
                    floatx4 z = {0.f,0.f,0.f,0.f};
                    d[nt] = __builtin_amdgcn_mfma_f32_16x16x32_f16(a, b[nt], z, 0,0,0);
                }
                #pragma unroll
                for (int nt = 0; nt < 4; ++nt)
                #pragma unroll
                for (int j = 0; j < 4; ++j) {
                    int wr = mt*16 + lh*4 + j;
                    *(_Float16*)(actc + wr*128 + ((((nt*16+l15)*2)) ^ ((wr&7)<<4))) =
                        (_Float16)silu_f(d[nt][j]);
                }
            }
        }
        __builtin_amdgcn_sched_barrier(0);

        // ---- L2, L3 ----
        const _Float16* Wl[2] = { sWt1, sWt2 };
        #pragma unroll
        for (int layer = 0; layer < 2; ++layer) {
            const char* wc = (const char*)Wl[layer];
            half8 b[4][2];
            #pragma unroll
            for (int nt = 0; nt < 4; ++nt)
            #pragma unroll
            for (int ks = 0; ks < 2; ++ks) {
                int n = nt*16 + l15;
                b[nt][ks] = *(half8*)(wc + n*128 + ((ks*64 + lh*16) ^ ((n&7)<<4)));
            }
            #pragma unroll
            for (int mt = 0; mt < 4; ++mt) {
                int rr = mt*16 + l15;
                half8 a0 = *(half8*)(actc + rr*128 + ((      lh*16) ^ ((rr&7)<<4)));
                half8 a1 = *(half8*)(actc + rr*128 + ((64 + lh*16) ^ ((rr&7)<<4)));
                floatx4 d[4];
                #pragma unroll
                for (int nt = 0; nt < 4; ++nt) {
                    floatx4 z = {0.f,0.f,0.f,0.f};
                    z = __builtin_amdgcn_mfma_f32_16x16x32_f16(a0, b[nt][0], z, 0,0,0);
                    d[nt] = __builtin_amdgcn_mfma_f32_16x16x32_f16(a1, b[nt][1], z, 0,0,0);
                }
                #pragma unroll
                for (int nt = 0; nt < 4; ++nt)
                #pragma unroll
                for (int j = 0; j < 4; ++j) {
                    int wr = mt*16 + lh*4 + j;
                    *(_Float16*)(actc + wr*128 + ((((nt*16+l15)*2)) ^ ((wr&7)<<4))) =
                        (_Float16)silu_f(d[nt][j]);
                }
            }
            __builtin_amdgcn_sched_barrier(0);
        }

        // ---- L4 -> w_out ----
        {
            half8 b[6][2];
            #pragma unroll
            for (int nt = 0; nt < 6; ++nt)
            #pragma unroll
            for (int ks = 0; ks < 2; ++ks) {
                int n = nt*16 + l15;
                b[nt][ks] = *(half8*)((char*)sWt3 + n*128 + ((ks*64 + lh*16) ^ ((n&7)<<4)));
            }
            #pragma unroll
            for (int mt = 0; mt < 4; ++mt) {
                int rr = mt*16 + l15;
                half8 a0 = *(half8*)(actc + rr*128 + ((      lh*16) ^ ((rr&7)<<4)));
                half8 a1 = *(half8*)(actc + rr*128 + ((64 + lh*16) ^ ((rr&7)<<4)));
                #pragma unroll
                for (int nt = 0; nt < 6; ++nt) {
                    floatx4 z = {0.f,0.f,0.f,0.f};
                    z = __builtin_amdgcn_mfma_f32_16x16x32_f16(a0, b[nt][0], z, 0,0,0);
                    floatx4 d = __builtin_amdgcn_mfma_f32_16x16x32_f16(a1, b[nt][1], z, 0,0,0);
                    #pragma unroll
                    for (int j = 0; j < 4; ++j) {
                        int e = c0 + mt*16 + lh*4 + j;
                        if (e < Eact)
                            w_out[(size_t)e*96 + nt*16 + l15] = (_Float16)d[j];
                    }
                }
            }
        }
        __builtin_amdgcn_sched_barrier(0);
    }
}

// ---------------- gather: 8 lanes per node, register segmented reduction (no atomics) ----------------
__global__ __launch_bounds__(256)
void k_gather(const int* __restrict__ rowptr, const int* __restrict__ eS,
              const float* __restrict__ pos,
              const float* __restrict__ h1, const _Float16* __restrict__ w_out,
              float* __restrict__ feats, int N)
{
    int g = threadIdx.x >> 3;            // group 0..31
    int j = threadIdx.x & 7;             // lane in group -> columns 4j..4j+3
    int n = blockIdx.x * 32 + g;
    if (n >= N) return;
    int c0 = j * 4;

    float acc[9][4];
    #pragma unroll
    for (int m = 0; m < 9; ++m)
        #pragma unroll
        for (int q = 0; q < 4; ++q) acc[m][q] = 0.f;

    float px = pos[3*n+0], py = pos[3*n+1], pz = pos[3*n+2];
    int lo = rowptr[n], hi = rowptr[n+1];

    for (int k = lo; k < hi; ++k) {
        int s = eS[k];
        float dx = px - pos[3*s+0];
        float dy = py - pos[3*s+1];
        float dz = pz - pos[3*s+2];
        float r  = sqrtf(dx*dx + dy*dy + dz*dz + 1e-12f);
        float inv_r = 1.0f / r;
        float ux = dx*inv_r, uy = dy*inv_r, uz = dz*inv_r;
        const float s3 = 1.73205081f, s5 = 2.23606798f, s15 = 3.87298335f;
        float sh[9];
        sh[0] = 1.0f;
        sh[1] = s3 * ux; sh[2] = s3 * uy; sh[3] = s3 * uz;
        sh[4] = s15 * ux * uy; sh[5] = s15 * uy * uz;
        sh[6] = 0.5f * s5 * (3.0f * uz * uz - 1.0f);
        sh[7] = s15 * ux * uz;
        sh[8] = 0.5f * s15 * (ux * ux - uy * uy);

        const _Float16* wp = w_out + (size_t)k * 96 + c0;
        half4 w0v = *(const half4*)(wp);
        half4 w1v = *(const half4*)(wp + 32);
        half4 w2v = *(const half4*)(wp + 64);
        float4 hv = *(const float4*)(h1 + (size_t)s * Cdim + c0);
        float hb[4] = {hv.x, hv.y, hv.z, hv.w};

        #pragma unroll
        for (int q = 0; q < 4; ++q) {
            float m0 = hb[q] * (float)w0v[q];
            float m1 = hb[q] * (float)w1v[q];
            float m2 = hb[q] * (float)w2v[q];
            acc[0][q] += m0;
            acc[1][q] += sh[1] * m1;
            acc[2][q] += sh[2] * m1;
            acc[3][q] += sh[3] * m1;
            acc[4][q] += sh[4] * m2;
            acc[5][q] += sh[5] * m2;
            acc[6][q] += sh[6] * m2;
            acc[7][q] += sh[7] * m2;
            acc[8][q] += sh[8] * m2;
        }
    }

    float* Ar = feats + (size_t)n * 576 + 288 + c0;
    #pragma unroll
    for (int m = 0; m < 9; ++m)
        *(float4*)(Ar + m * Cdim) = make_float4(acc[m][0], acc[m][1], acc[m][2], acc[m][3]);
}

// ---------------- out[n,m,:] = (A[n,m,:]/16) @ Wprod[L[m]]  for m=1..8 ----------------
__global__ __launch_bounds__(256)
void k_out_m(float* AO, const float* __restrict__ Wprod, int N, int outslot)
{
    __shared__ float sW[3 * Cdim * Cdim];
    for (int t = threadIdx.x; t < 3 * Cdim * Cdim; t += 256) sW[t] = Wprod[t];
    __syncthreads();
    int t = blockIdx.x * blockDim.x + threadIdx.x;
    if (t >= N * 8) return;
    int m = (t & 7) + 1;
    int n = t >> 3;
    int l = (m <= 3) ? 1 : 2;
    const float* Ar = AO + (size_t)n * 576 + 288 + m * Cdim;
    float Av[Cdim];
    #pragma unroll
    for (int c4 = 0; c4 < 8; ++c4) {
        float4 v = *(const float4*)(Ar + c4 * 4);
        Av[c4*4+0]=v.x*0.0625f; Av[c4*4+1]=v.y*0.0625f;
        Av[c4*4+2]=v.z*0.0625f; Av[c4*4+3]=v.w*0.0625f;
    }
    float acc[Cdim];
    #pragma unroll
    for (int d = 0; d < Cdim; ++d) acc[d] = 0.f;
    const float* wbase = sW + l * Cdim * Cdim;
    #pragma unroll
    for (int c = 0; c < Cdim; ++c) {
        float av = Av[c];
        #pragma unroll
        for (int d = 0; d < Cdim; ++d) acc[d] += av * wbase[c * Cdim + d];
    }
    float* o = AO + (size_t)n * 576 + outslot + m * Cdim;
    #pragma unroll
    for (int d4 = 0; d4 < 8; ++d4)
        *(float4*)(o + d4 * 4) = make_float4(acc[d4*4], acc[d4*4+1], acc[d4*4+2], acc[d4*4+3]);
}

// ---------------- per-node scalar channel ----------------
template<int ITER>
__global__ __launch_bounds__(256)
void k_node_scalar(float* AO, const float* h, const int* __restrict__ elem,
                   const float* __restrict__ Wprod0, const float* __restrict__ Wsc,
                   const float* __restrict__ Wp, const float* __restrict__ w_ro1,
                   const float* __restrict__ W_m1, const float* __restrict__ w_m2,
                   float* __restrict__ energy, int N, int outslot)
{
    __shared__ float sW0[Cdim * Cdim];
    __shared__ float sM1[Cdim * 16];
    __shared__ float sm2[16];
    __shared__ float sro[Cdim];
    for (int t = threadIdx.x; t < Cdim * Cdim; t += 256) sW0[t] = Wprod0[t];
    for (int t = threadIdx.x; t < Cdim * 16; t += 256) sM1[t] = W_m1[t];
    if (threadIdx.x < 16) sm2[threadIdx.x] = w_m2[threadIdx.x];
    if (threadIdx.x < Cdim) sro[threadIdx.x] = w_ro1[threadIdx.x];
    __syncthreads();
    int n = blockIdx.x * blockDim.x + threadIdx.x;
    if (n >= N) return;
    int el = elem[n];
    const float* Ar = AO + (size_t)n * 576 + 288;
    float A0[Cdim], hv[Cdim];
    #pragma unroll
    for (int c4 = 0; c4 < 8; ++c4) {
        float4 v = *(const float4*)(Ar + c4 * 4);
        A0[c4*4+0]=v.x*0.0625f; A0[c4*4+1]=v.y*0.0625f;
        A0[c4*4+2]=v.z*0.0625f; A0[c4*4+3]=v.w*0.0625f;
        float4 w = *(const float4*)(h + (size_t)n * 576 + c4 * 4);
        hv[c4*4+0]=w.x; hv[c4*4+1]=w.y; hv[c4*4+2]=w.z; hv[c4*4+3]=w.w;
    }
    float hs[Cdim];
    #pragma unroll
    for (int d = 0; d < Cdim; ++d) hs[d] = 0.f;
    #pragma unroll
    for (int c = 0; c < Cdim; ++c) {
        float av = A0[c];
        #pragma unroll
        for (int d = 0; d < Cdim; ++d) hs[d] += av * sW0[c * Cdim + d];
    }
    const float* Ws = Wsc + (size_t)el * Cdim * Cdim;
    #pragma unroll
    for (int c = 0; c < Cdim; ++c) {
        float hc = hv[c];
        #pragma unroll
        for (int d = 0; d < Cdim; ++d) hs[d] += hc * Ws[c * Cdim + d];
    }
    const float* wp0 = Wp + 0 * (ZDIM * Cdim) + el * Cdim;
    const float* wp1 = Wp + 1 * (ZDIM * Cdim) + el * Cdim;
    const float* wp2 = Wp + 2 * (ZDIM * Cdim) + el * Cdim;
    #pragma unroll
    for (int d = 0; d < Cdim; ++d) {
        float A = A0[d], A2 = A * A;
        hs[d] += wp0[d] * A + wp1[d] * A2 + wp2[d] * (A2 * A);
    }
    float eadd;
    if (ITER == 0) {
        float acc = 0.f;
        #pragma unroll
        for (int d = 0; d < Cdim; ++d) acc += hs[d] * sro[d];
        eadd = acc;
    } else {
        float acc = 0.f;
        #pragma unroll
        for (int j = 0; j < 16; ++j) {
            float tj = 0.f;
            #pragma unroll
            for (int d = 0; d < Cdim; ++d) tj += hs[d] * sM1[d * 16 + j];
            acc += silu_f(tj) * sm2[j];
        }
        eadd = acc;
    }
    energy[n] += eadd;
    float* o = AO + (size_t)n * 576 + outslot;
    #pragma unroll
    for (int d4 = 0; d4 < 8; ++d4)
        *(float4*)(o + d4 * 4) = make_float4(hs[d4*4], hs[d4*4+1], hs[d4*4+2], hs[d4*4+3]);
}

extern "C" void kernel_launch(void* const* d_in, const int* in_sizes, int n_in,
                              void* d_out, int out_size, void* d_ws, size_t ws_size,
                              hipStream_t stream)
{
    const float* attrs   = (const float*)d_in[0];
    const float* pos     = (const float*)d_in[1];
    const int*   snd     = (const int*)d_in[2];
    const int*   rcv     = (const int*)d_in[3];
    const float* W_embed = (const float*)d_in[4];
    const float* atomE   = (const float*)d_in[5];
    const float* Wr0     = (const float*)d_in[6];
    const float* Wr1     = (const float*)d_in[7];
    const float* Wr2     = (const float*)d_in[8];
    const float* Wr3     = (const float*)d_in[9];
    const float* Wlin    = (const float*)d_in[10];
    const float* Wsc     = (const float*)d_in[11];
    const float* Wprod   = (const float*)d_in[12];
    const float* Wp      = (const float*)d_in[13];
    const float* w_ro1   = (const float*)d_in[14];
    const float* W_m1    = (const float*)d_in[15];
    const float* w_m2    = (const float*)d_in[16];

    const int N = in_sizes[1] / 3;
    const int E = in_sizes[2];

    float* energy = (float*)d_out;
    float* feats  = (float*)d_out + N;

    char* ws = (char*)d_ws;
    size_t off = 0;
    auto alloc = [&](size_t bytes) { void* p = ws + off; off = (off + bytes + 255) & ~(size_t)255; return p; };
    int* deg    = (int*)alloc((size_t)N * 4);
    int* cursor = (int*)alloc((size_t)N * 4);
    int* rowptr = (int*)alloc((size_t)(N + 1) * 4);
    int* eS     = (int*)alloc((size_t)E * 4);
    int* eT     = (int*)alloc((size_t)E * 4);
    int* elem   = (int*)alloc((size_t)N * 4);
    float* h1   = (float*)alloc((size_t)N * Cdim * 4);
    _Float16* w_out = (_Float16*)(ws + off);

    k_node_init<<<(N + 255)/256, 256, 0, stream>>>(attrs, W_embed, atomE, elem, feats, energy, deg, N);
    k_edge_zbl<<<(E + 255)/256, 256, 0, stream>>>(pos, snd, rcv, elem, energy, deg, E);
    k_scan<<<1, 1024, 0, stream>>>(deg, rowptr, cursor, N);
    k_place<<<(E + 255)/256, 256, 0, stream>>>(pos, snd, rcv, cursor, eS, eT, E);

    const int NBLK = (N + 31) / 32;
    for (int i = 0; i < 2; ++i) {
        k_h1<<<(N + 255)/256, 256, 0, stream>>>(feats, Wlin + i * Cdim * Cdim, h1, N);
        k_mlp<<<512, 256, 0, stream>>>(eS, eT, pos,
            Wr0 + i * NBES * HDIM, Wr1 + i * HDIM * HDIM,
            Wr2 + i * HDIM * HDIM, Wr3 + i * HDIM * 96,
            rowptr + N, w_out);
        k_gather<<<NBLK, 256, 0, stream>>>(rowptr, eS, pos, h1, w_out, feats, N);
        k_out_m<<<(N*8 + 255)/256, 256, 0, stream>>>(feats, Wprod + i * 3 * Cdim * Cdim,
                                                     N, (i == 0) ? 0 : 288);
        if (i == 0)
            k_node_scalar<0><<<(N + 255)/256, 256, 0, stream>>>(feats, feats, elem,
                Wprod + 0 * 3072, Wsc + 0 * 10240, Wp + 0 * 960,
                w_ro1, W_m1, w_m2, energy, N, 0);
        else
            k_node_scalar<1><<<(N + 255)/256, 256, 0, stream>>>(feats, feats, elem,
                Wprod + 1 * 3072, Wsc + 1 * 10240, Wp + 1 * 960,
                w_ro1, W_m1, w_m2, energy, N, 288);
    }
}